// Round 12
// baseline (916.818 us; speedup 1.0000x reference)
//
#include <hip/hip_runtime.h>
#include <stdint.h>

constexpr int LAYERS = 6;
constexpr int Bc = 2, Sc = 2048, Dc = 512, Hc = 8, DHc = 64, FFc = 2048;
constexpr int Mc = Bc * Sc;  // 4096
constexpr int NS = 2;        // attention K-splits
constexpr int KCHUNK = Sc / NS;  // 1024

typedef __attribute__((ext_vector_type(8))) __bf16 bf16x8;
typedef __attribute__((ext_vector_type(4))) __bf16 bf16x4;
typedef __attribute__((ext_vector_type(4))) float f32x4;

__device__ __forceinline__ void async_ld16(const void* g, void* lds) {
  __builtin_amdgcn_global_load_lds(
      (const __attribute__((address_space(1))) uint32_t*)g,
      (__attribute__((address_space(3))) uint32_t*)lds, 16, 0, 0);
}

// ---------------- fused fp32 -> bf16 conversion of all inputs ----------------
// Segments: Wq | Wo | fw1 | fw2 | query(+f32 copy) | key
__global__ __launch_bounds__(256) void cvt_all(
    const float* __restrict__ Wq, const float* __restrict__ Wo,
    const float* __restrict__ fw1, const float* __restrict__ fw2,
    const float* __restrict__ query, const float* __restrict__ key,
    __bf16* __restrict__ wq_b, __bf16* __restrict__ wo_b,
    __bf16* __restrict__ w1_b, __bf16* __restrict__ w2_b,
    __bf16* __restrict__ x_b, __bf16* __restrict__ key_b,
    float* __restrict__ x_f) {
  size_t i = ((size_t)blockIdx.x * 256 + threadIdx.x) * 4;
  constexpr size_t nW = (size_t)LAYERS * Dc * Dc;   // 1572864
  constexpr size_t nF = (size_t)LAYERS * FFc * Dc;  // 6291456
  constexpr size_t nX = (size_t)Mc * Dc;            // 2097152
  const float* src;
  __bf16* dst;
  float* fdst = nullptr;
  if (i < nW) { src = Wq + i; dst = wq_b + i; }
  else if (i < 2 * nW) { size_t j = i - nW; src = Wo + j; dst = wo_b + j; }
  else if (i < 2 * nW + nF) { size_t j = i - 2 * nW; src = fw1 + j; dst = w1_b + j; }
  else if (i < 2 * nW + 2 * nF) { size_t j = i - 2 * nW - nF; src = fw2 + j; dst = w2_b + j; }
  else if (i < 2 * nW + 2 * nF + nX) {
    size_t j = i - 2 * nW - 2 * nF;
    src = query + j; dst = x_b + j; fdst = x_f + j;
  } else {
    size_t j = i - 2 * nW - 2 * nF - nX;
    src = key + j; dst = key_b + j;
  }
  const float4 v = *(const float4*)src;
  bf16x4 o;
  o[0] = (__bf16)v.x; o[1] = (__bf16)v.y; o[2] = (__bf16)v.z; o[3] = (__bf16)v.w;
  *(bf16x4*)dst = o;
  if (fdst) *(float4*)fdst = v;
}

// interleave all layers' Wk,Wv into one bf16 buffer [L][2][D][D]
__global__ __launch_bounds__(256) void cvt_kv_kernel(const float* __restrict__ Wk,
                                                     const float* __restrict__ Wv,
                                                     __bf16* __restrict__ out) {
  size_t i = ((size_t)blockIdx.x * 256 + threadIdx.x) * 4;
  int n = (int)(i / ((size_t)Dc * Dc));  // lyr*2 + p
  int lyr = n >> 1, p = n & 1;
  size_t idx = i - (size_t)n * Dc * Dc;
  const float* src = (p ? Wv : Wk) + (size_t)lyr * Dc * Dc + idx;
  const float4 v = *(const float4*)src;
  bf16x4 o;
  o[0] = (__bf16)v.x; o[1] = (__bf16)v.y; o[2] = (__bf16)v.z; o[3] = (__bf16)v.w;
  *(bf16x4*)(out + i) = o;
}

// key mask -> additive bias
__global__ __launch_bounds__(256) void kbias_kernel(const int* __restrict__ km,
                                                    float* __restrict__ kb, int n) {
  int i = blockIdx.x * 256 + threadIdx.x;
  if (i < n) kb[i] = km[i] ? 0.f : -1e30f;
}

// ---------------- GEMM: C[M,N] = A[M,K] @ W[N,K]^T + bias, fused epilogues ----
// BK=64, 2-phase double-buffered LDS, both-sides XOR swizzle (slot ^ (row&7)).
// Split-K via blockIdx.z: K = per-block chunk, Kstride = full row stride.
// EPI: 0 = f32 row-major partial (outf + z*M*N), bias at z==0
//      4 = bf16 row-major, leaky-relu(0.01)              (FFN1)
//      6 = batched KV: N = L*1024; K -> outb [L,B,H,S,DH];
//          V -> outb2 [L,B,H,DH,S] via LDS-transposed coalesced stores
template <int BM, int BN, int WM, int WN, int EPI>
__global__ __launch_bounds__(256) void gemm_bt(
    const __bf16* __restrict__ A, const __bf16* __restrict__ W,
    const float* __restrict__ bias, const float* __restrict__ bias2,
    float* __restrict__ outf, __bf16* __restrict__ outb,
    __bf16* __restrict__ outb2, float scale,
    int M, int N, int K, int Kstride) {
  constexpr int BK = 64;
  __shared__ __bf16 As[2][BM * BK];
  __shared__ __bf16 Bs[2][BN * BK];
  const int tid = threadIdx.x;
  const int l15 = tid & 15;
  const int lg = (tid & 63) >> 4;
  const int w = tid >> 6;
  const int wm = w >> 1, wn = w & 1;
  const int tm = blockIdx.y * BM;
  const int tn = blockIdx.x * BN;
  const int z = blockIdx.z;
  const __bf16* Ap = A + (size_t)tm * Kstride + (size_t)z * K;
  const __bf16* Wp = W + (size_t)tn * Kstride + (size_t)z * K;
  f32x4 acc[WM][WN] = {};

  auto stage = [&](int k0, int bf) {
#pragma unroll
    for (int c = 0; c < BM * 8 / 256; ++c) {
      int cc = c * 256 + tid;
      int r = cc >> 3, s = cc & 7;
      int ss = s ^ (r & 7);  // inverse-swizzled source slot
      async_ld16(Ap + (size_t)r * Kstride + k0 + ss * 8, &As[bf][cc * 8]);
    }
#pragma unroll
    for (int c = 0; c < BN * 8 / 256; ++c) {
      int cc = c * 256 + tid;
      int r = cc >> 3, s = cc & 7;
      int ss = s ^ (r & 7);
      async_ld16(Wp + (size_t)r * Kstride + k0 + ss * 8, &Bs[bf][cc * 8]);
    }
  };

  const int nk = K / BK;
  stage(0, 0);
  __syncthreads();
  int buf = 0;
  for (int t = 0; t < nk; ++t) {
    if (t + 1 < nk) stage((t + 1) * BK, buf ^ 1);
    bf16x8 af[WM][2], bfr[WN][2];
#pragma unroll
    for (int i = 0; i < WM; ++i) {
      int row = wm * WM * 16 + i * 16 + l15;
#pragma unroll
      for (int kf = 0; kf < 2; ++kf)
        af[i][kf] = *(const bf16x8*)&As[buf][row * 64 + (((kf * 4 + lg) ^ (row & 7)) * 8)];
    }
#pragma unroll
    for (int j = 0; j < WN; ++j) {
      int row = wn * WN * 16 + j * 16 + l15;
#pragma unroll
      for (int kf = 0; kf < 2; ++kf)
        bfr[j][kf] = *(const bf16x8*)&Bs[buf][row * 64 + (((kf * 4 + lg) ^ (row & 7)) * 8)];
    }
#pragma unroll
    for (int kf = 0; kf < 2; ++kf)
#pragma unroll
      for (int i = 0; i < WM; ++i)
#pragma unroll
        for (int j = 0; j < WN; ++j)
          acc[i][j] = __builtin_amdgcn_mfma_f32_16x16x32_bf16(af[i][kf], bfr[j][kf], acc[i][j], 0, 0, 0);
    __syncthreads();
    buf ^= 1;
  }

  if constexpr (EPI == 6) {
    const bool isV = ((tn & 1023) >= 512);
    const int lyr = tn >> 10;
    const int b = tm >> 11;
    const int sbase = tm & (Sc - 1);
    if (isV) {
      // V half: transpose 64(s) x 128(d) tile through LDS, coalesced stores.
      __bf16* T = (__bf16*)&As[0][0];  // [128 d][64 s], 16B-slot XOR swizzle
#pragma unroll
      for (int i = 0; i < WM; ++i) {
#pragma unroll
        for (int j = 0; j < WN; ++j) {
          const int d = wn * WN * 16 + j * 16 + l15;   // 0..127
          const int dg = (tn & 511) + d;               // 0..511 within layer V
          const float bv = bias2[lyr * 512 + dg];
          const int s0 = wm * WM * 16 + i * 16 + lg * 4;
          bf16x4 pk;
#pragma unroll
          for (int r = 0; r < 4; ++r) pk[r] = (__bf16)(acc[i][j][r] + bv);
          const int slot = (s0 >> 3) ^ (d & 7);
          *(bf16x4*)&T[d * 64 + slot * 8 + (s0 & 7)] = pk;
        }
      }
      __syncthreads();
      const int rr = tid >> 3;   // 0..31
      const int c8 = tid & 7;    // s-slot
#pragma unroll
      for (int pass = 0; pass < 4; ++pass) {
        const int d = pass * 32 + rr;
        const int slot = c8 ^ (d & 7);
        bf16x8 v8 = *(const bf16x8*)&T[d * 64 + slot * 8];
        const int dg = (tn & 511) + d;
        const int h = dg >> 6, dh = dg & 63;
        *(bf16x8*)&outb2[((((size_t)(lyr * Bc + b) * Hc + h)) * DHc + dh) * Sc +
                         sbase + c8 * 8] = v8;
      }
    } else {
      // K half: near-coalesced direct stores
#pragma unroll
      for (int i = 0; i < WM; ++i) {
#pragma unroll
        for (int j = 0; j < WN; ++j) {
          const int d = wn * WN * 16 + j * 16 + l15;
          const int dg = (tn & 511) + d;
          const float bv = bias[lyr * 512 + dg];
          const int h = dg >> 6, dh = dg & 63;
#pragma unroll
          for (int r = 0; r < 4; ++r) {
            const int s = sbase + wm * WM * 16 + i * 16 + lg * 4 + r;
            outb[((((size_t)(lyr * Bc + b) * Hc + h)) * Sc + s) * DHc + dh] =
                (__bf16)(acc[i][j][r] + bv);
          }
        }
      }
    }
    return;
  }

#pragma unroll
  for (int i = 0; i < WM; ++i) {
#pragma unroll
    for (int j = 0; j < WN; ++j) {
      const int n = tn + wn * WN * 16 + j * 16 + l15;
      float bv;
      if constexpr (EPI == 0) {
        bv = (z == 0) ? bias[n] : 0.f;
      } else {
        bv = bias[n];
      }
#pragma unroll
      for (int r = 0; r < 4; ++r) {
        const int m = tm + wm * WM * 16 + i * 16 + lg * 4 + r;
        float v = acc[i][j][r] + bv;
        if constexpr (EPI == 0) {
          outf[(size_t)z * M * N + (size_t)m * N + n] = v;
        } else if constexpr (EPI == 4) {
          float lv = v > 0.f ? v : 0.01f * v;
          outb[(size_t)m * N + n] = (__bf16)lv;
        }
      }
    }
  }
}

// ---------------- flash attention with K-split, swapped QK^T ----------------
// Fused Q-projection prologue: Q^T = mfma(Wq_head rows, x rows) with operands
// read directly from L2 (no LDS), then bias + 0.125 scale + crossbar exchange
// into the qf B-operand layout. Main loop: S = mfma(K, Q) so each lane holds
// P[k-chunk][q=lane&15]; P never round-trips LDS. K,V staged in LDS
// (double-buffered, swizzled). XCD-chunked block swizzle for L2 residency.
__global__ __launch_bounds__(256, 5) void attn_kernel(
    const __bf16* __restrict__ xq, const __bf16* __restrict__ wq,
    const float* __restrict__ bq, const __bf16* __restrict__ k,
    const __bf16* __restrict__ vt, const float* __restrict__ kb,
    __bf16* __restrict__ Opart, float* __restrict__ mpart,
    float* __restrict__ lpart) {
  const int bid = blockIdx.x;
  const int o = (bid & 7) * 128 + (bid >> 3);  // bijective (1024 = 8*128)
  const int qb = o & 31;
  const int p = o >> 5;      // 0..31 = bh*NS + z
  const int bh = p >> 1;
  const int z = p & 1;
  const int b = bh >> 3;
  const int h = bh & 7;
  const int w = threadIdx.x >> 6;
  const int l = threadIdx.x & 63;
  const int l15 = l & 15;
  const int lg = l >> 4;
  const int tid = threadIdx.x;
  const int qbase = qb * 64 + w * 16;
  const int k0 = z * KCHUNK;

  const __bf16* kp = k + (size_t)bh * Sc * DHc;
  const __bf16* vp = vt + (size_t)bh * DHc * Sc;
  const float* kbp = kb + (size_t)b * Sc;

  __shared__ __bf16 Ks[2][4096];
  __shared__ __bf16 Vs[2][4096];

  auto stage = [&](int t, int bf) {
    const int kt = k0 + t * 64;
#pragma unroll
    for (int ii = 0; ii < 2; ++ii) {
      int i = ii * 256 + tid;          // 16B slot id, 0..511
      int r = i >> 3;                  // row 0..63
      int bsrc = (i & 7) ^ (r & 7);    // inverse-swizzled source slot
      async_ld16(kp + (size_t)(kt + r) * DHc + bsrc * 8, &Ks[bf][i * 8]);
      async_ld16(vp + (size_t)r * Sc + kt + bsrc * 8, &Vs[bf][i * 8]);
    }
  };

  stage(0, 0);  // issue early; latency hides under the Q-proj prologue

  const int srcA = ((lg & 1) * 2) * 16 + l15;
  const int srcB = srcA + 16;
  const bool hi = (lg >> 1) & 1;

  // ---- fused Q projection: Q^T[dh][q] = Wq_h @ x^T, straight from L2 ----
  f32x4 qacc[4] = {};
  {
    const __bf16* xrow = xq + ((size_t)(b * Sc + qbase + l15)) * Dc;
    const __bf16* wqh = wq + ((size_t)(h * DHc)) * Dc;
#pragma unroll
    for (int ks = 0; ks < 16; ++ks) {
      bf16x8 bfrag = *(const bf16x8*)(xrow + ks * 32 + lg * 8);
#pragma unroll
      for (int dt = 0; dt < 4; ++dt) {
        bf16x8 afrag = *(const bf16x8*)(wqh + (size_t)(dt * 16 + l15) * Dc + ks * 32 + lg * 8);
        qacc[dt] = __builtin_amdgcn_mfma_f32_16x16x32_bf16(afrag, bfrag, qacc[dt], 0, 0, 0);
      }
    }
  }
  // bias + scale, pack pairs to bf16 words
  unsigned pk[4][2];
#pragma unroll
  for (int dt = 0; dt < 4; ++dt) {
    const float4 bq4 = *(const float4*)&bq[h * DHc + dt * 16 + lg * 4];
    union { __bf16 hh[2]; unsigned u; } cu;
    cu.hh[0] = (__bf16)((qacc[dt][0] + bq4.x) * 0.125f);
    cu.hh[1] = (__bf16)((qacc[dt][1] + bq4.y) * 0.125f);
    pk[dt][0] = cu.u;
    cu.hh[0] = (__bf16)((qacc[dt][2] + bq4.z) * 0.125f);
    cu.hh[1] = (__bf16)((qacc[dt][3] + bq4.w) * 0.125f);
    pk[dt][1] = cu.u;
  }
  // crossbar: qf[kf] dword w = pk[kf*2+(lg>>1)][w&1] from src lane (w>>1 ? srcB : srcA)
  bf16x8 qf[2];
#pragma unroll
  for (int kf = 0; kf < 2; ++kf) {
    unsigned a0 = __shfl((int)pk[kf * 2][0], srcA, 64);
    unsigned a1 = __shfl((int)pk[kf * 2][1], srcA, 64);
    unsigned a2 = __shfl((int)pk[kf * 2][0], srcB, 64);
    unsigned a3 = __shfl((int)pk[kf * 2][1], srcB, 64);
    unsigned b0 = __shfl((int)pk[kf * 2 + 1][0], srcA, 64);
    unsigned b1 = __shfl((int)pk[kf * 2 + 1][1], srcA, 64);
    unsigned b2 = __shfl((int)pk[kf * 2 + 1][0], srcB, 64);
    unsigned b3 = __shfl((int)pk[kf * 2 + 1][1], srcB, 64);
    union { unsigned u[4]; bf16x8 v; } qq;
    qq.u[0] = hi ? b0 : a0;
    qq.u[1] = hi ? b1 : a1;
    qq.u[2] = hi ? b2 : a2;
    qq.u[3] = hi ? b3 : a3;
    qf[kf] = qq.v;
  }

  bf16x8 onesf;
#pragma unroll
  for (int i = 0; i < 8; ++i) onesf[i] = (__bf16)1.0f;

  f32x4 oacc[4] = {};
  f32x4 lacc = {};
  float mr = -1e30f;  // running max for q = l15 (converged across lane groups)

  __syncthreads();

  constexpr int NT = KCHUNK / 64;
  int buf = 0;
  for (int t = 0; t < NT; ++t) {
    const int kt = k0 + t * 64;
    if (t + 1 < NT) stage(t + 1, buf ^ 1);

    // mask bias for this tile: k = cb*16 + lg*4 + r  ->  4 aligned float4 loads
    float4 mb4[4];
#pragma unroll
    for (int cb = 0; cb < 4; ++cb)
      mb4[cb] = *(const float4*)&kbp[kt + cb * 16 + lg * 4];

    // ---- swapped QK^T: S[k][q], lane holds k=cb*16+lg*4+r, q=l15 ----
    f32x4 sacc[4] = {};
    __builtin_amdgcn_s_setprio(1);
#pragma unroll
    for (int kf = 0; kf < 2; ++kf) {
#pragma unroll
      for (int cb = 0; cb < 4; ++cb) {
        int row = cb * 16 + l15;
        bf16x8 kfr = *(const bf16x8*)&Ks[buf][row * 64 + (((kf * 4 + lg) ^ (row & 7)) * 8)];
        sacc[cb] = __builtin_amdgcn_mfma_f32_16x16x32_bf16(kfr, qf[kf], sacc[cb], 0, 0, 0);
      }
    }
    __builtin_amdgcn_s_setprio(0);
    sacc[0][0] += mb4[0].x; sacc[0][1] += mb4[0].y; sacc[0][2] += mb4[0].z; sacc[0][3] += mb4[0].w;
    sacc[1][0] += mb4[1].x; sacc[1][1] += mb4[1].y; sacc[1][2] += mb4[1].z; sacc[1][3] += mb4[1].w;
    sacc[2][0] += mb4[2].x; sacc[2][1] += mb4[2].y; sacc[2][2] += mb4[2].z; sacc[2][3] += mb4[2].w;
    sacc[3][0] += mb4[3].x; sacc[3][1] += mb4[3].y; sacc[3][2] += mb4[3].z; sacc[3][3] += mb4[3].w;

    // ---- row max: 15 local fmax + 2 shfl_xor (lanes with same l15) ----
    float mx = sacc[0][0];
#pragma unroll
    for (int cb = 0; cb < 4; ++cb)
#pragma unroll
      for (int r = 0; r < 4; ++r) mx = fmaxf(mx, sacc[cb][r]);
    mx = fmaxf(mx, __shfl_xor(mx, 16, 64));
    mx = fmaxf(mx, __shfl_xor(mx, 32, 64));

    if (__any(mx > mr + 8.f)) {   // defer-max: rare rescale
      float mn = fmaxf(mr, mx);
      float f = __expf(mr - mn);
      mr = mn;
      // redistribute f (held at lane l15=q) to output layout q = lg*4+j
      float fj[4];
#pragma unroll
      for (int j = 0; j < 4; ++j) fj[j] = __shfl(f, lg * 4 + j, 64);
#pragma unroll
      for (int j = 0; j < 4; ++j) lacc[j] *= fj[j];
#pragma unroll
      for (int db = 0; db < 4; ++db)
#pragma unroll
        for (int j = 0; j < 4; ++j) oacc[db][j] *= fj[j];
    }

    // ---- P = exp(S - m), pack to bf16 words pw[cb][w2] ----
    unsigned pw[4][2];
#pragma unroll
    for (int cb = 0; cb < 4; ++cb) {
#pragma unroll
      for (int w2 = 0; w2 < 2; ++w2) {
        union { __bf16 hh[2]; unsigned u; } cu;
        cu.hh[0] = (__bf16)__expf(sacc[cb][2 * w2] - mr);
        cu.hh[1] = (__bf16)__expf(sacc[cb][2 * w2 + 1] - mr);
        pw[cb][w2] = cu.u;
      }
    }

    // ---- in-register exchange: build PV A-fragment P[q=l15][k=kf*32+lg*8+e]
#pragma unroll
    for (int kf = 0; kf < 2; ++kf) {
      unsigned t0a = __shfl((int)pw[kf * 2][0], srcA, 64);
      unsigned t0b = __shfl((int)pw[kf * 2 + 1][0], srcA, 64);
      unsigned t1a = __shfl((int)pw[kf * 2][1], srcA, 64);
      unsigned t1b = __shfl((int)pw[kf * 2 + 1][1], srcA, 64);
      unsigned t2a = __shfl((int)pw[kf * 2][0], srcB, 64);
      unsigned t2b = __shfl((int)pw[kf * 2 + 1][0], srcB, 64);
      unsigned t3a = __shfl((int)pw[kf * 2][1], srcB, 64);
      unsigned t3b = __shfl((int)pw[kf * 2 + 1][1], srcB, 64);
      union { unsigned u[4]; bf16x8 v; } pa;
      pa.u[0] = hi ? t0b : t0a;
      pa.u[1] = hi ? t1b : t1a;
      pa.u[2] = hi ? t2b : t2a;
      pa.u[3] = hi ? t3b : t3a;
      __builtin_amdgcn_s_setprio(1);
      lacc = __builtin_amdgcn_mfma_f32_16x16x32_bf16(pa.v, onesf, lacc, 0, 0, 0);
#pragma unroll
      for (int db = 0; db < 4; ++db) {
        int row = db * 16 + l15;
        bf16x8 vf = *(const bf16x8*)&Vs[buf][row * 64 + (((kf * 4 + lg) ^ (row & 7)) * 8)];
        oacc[db] = __builtin_amdgcn_mfma_f32_16x16x32_bf16(pa.v, vf, oacc[db], 0, 0, 0);
      }
      __builtin_amdgcn_s_setprio(0);
    }
    __syncthreads();   // drains stage(t+1) vmem writes + protects buf reuse
    buf ^= 1;
  }

  // ---- write unnormalized partial ----
  const size_t obase = (((size_t)(z * Bc * Hc + bh)) * Sc + qbase) * DHc;
#pragma unroll
  for (int db = 0; db < 4; ++db)
#pragma unroll
    for (int j = 0; j < 4; ++j)
      Opart[obase + (size_t)(lg * 4 + j) * DHc + db * 16 + l15] = (__bf16)oacc[db][j];
  const int row0 = (z * Bc * Hc + bh) * Sc + qbase;
  if (lg == 0) mpart[row0 + l15] = mr;      // m held at lane l15 = q
  if (l15 == 0) {
#pragma unroll
    for (int j = 0; j < 4; ++j) lpart[row0 + lg * 4 + j] = lacc[j];
  }
}

// ---------------- combine split partials -> bf16 [B,S,D] (vectorized) -------
__global__ __launch_bounds__(256) void attn_combine(
    const __bf16* __restrict__ Opart, const float* __restrict__ mpart,
    const float* __restrict__ lpart, __bf16* __restrict__ out) {
  int t = blockIdx.x * 256 + threadIdx.x;  // over BH*S*8 (8 elems per thread)
  int g = t & 7;
  int row = t >> 3;          // bh*Sc + s
  int bh = row >> 11, s = row & (Sc - 1);
  constexpr int RSTRIDE = Bc * Hc * Sc;  // rows per split
  float m0 = mpart[row], m1 = mpart[RSTRIDE + row];
  float l0 = lpart[row], l1 = lpart[RSTRIDE + row];
  float M = fmaxf(m0, m1);
  float e0 = __expf(m0 - M), e1 = __expf(m1 - M);
  float inv = 1.0f / (e0 * l0 + e1 * l1);
  bf16x8 o0 = *(const bf16x8*)&Opart[(size_t)row * DHc + g * 8];
  bf16x8 o1 = *(const bf16x8*)&Opart[((size_t)RSTRIDE + row) * DHc + g * 8];
  bf16x8 r;
#pragma unroll
  for (int e = 0; e < 8; ++e)
    r[e] = (__bf16)((e0 * (float)o0[e] + e1 * (float)o1[e]) * inv);
  int b = bh >> 3, h = bh & 7;
  *(bf16x8*)&out[(((size_t)b * Sc + s)) * Dc + h * DHc + g * 8] = r;
}

// ---------------- residual add + LayerNorm (vectorized, 2 rows/block) -------
// x_out = LN((res + res2) * mask + xin) * g + b ; writes fp32 and bf16.
__global__ __launch_bounds__(256) void add_ln_kernel(
    const float* __restrict__ res, const float* __restrict__ res2,
    const int* __restrict__ rmask, const float* __restrict__ xin,
    const float* __restrict__ g, const float* __restrict__ bb,
    float* __restrict__ xo, __bf16* __restrict__ xbo) {
  const int tid = threadIdx.x;
  const int rl = tid >> 7;                 // row within pair (0/1)
  const int row = blockIdx.x * 2 + rl;
  const int ci = (tid & 127) * 4;          // column start
  const size_t base = (size_t)row * Dc + ci;
  const float4 a = *(const float4*)(res + base);
  const float4 a2 = *(const float4*)(res2 + base);
  const float4 xv = *(const float4*)(xin + base);
  const float mfac = (float)rmask[row];
  float4 v;
  v.x = (a.x + a2.x) * mfac + xv.x;
  v.y = (a.y + a2.y) * mfac + xv.y;
  v.z = (a.z + a2.z) * mfac + xv.z;
  v.w = (a.w + a2.w) * mfac + xv.w;
  float s = v.x + v.y + v.z + v.w;
#pragma unroll
  for (int d = 1; d < 64; d <<= 1) s += __shfl_xor(s, d, 64);
  __shared__ float red[4], red2[4];
  if ((tid & 63) == 0) red[tid >> 6] = s;
  __syncthreads();
  float mean = (red[rl * 2] + red[rl * 2 + 1]) * (1.0f / Dc);
  float4 dv;
  dv.x = v.x - mean; dv.y = v.y - mean; dv.z = v.z - mean; dv.w = v.w - mean;
  float qq = dv.x * dv.x + dv.y * dv.y + dv.z * dv.z + dv.w * dv.w;
#pragma unroll
  for (int d = 1; d < 64; d <<= 1) qq += __shfl_xor(qq, d, 64);
  if ((tid & 63) == 0) red2[tid >> 6] = qq;
  __syncthreads();
  float var = (red2[rl * 2] + red2[rl * 2 + 1]) * (1.0f / Dc);
  float rs = rsqrtf(var + 1e-5f);
  const float4 gv = *(const float4*)(g + ci);
  const float4 bv = *(const float4*)(bb + ci);
  float4 ov;
  ov.x = dv.x * rs * gv.x + bv.x;
  ov.y = dv.y * rs * gv.y + bv.y;
  ov.z = dv.z * rs * gv.z + bv.z;
  ov.w = dv.w * rs * gv.w + bv.w;
  *(float4*)(xo + base) = ov;
  bf16x4 ob;
  ob[0] = (__bf16)ov.x; ob[1] = (__bf16)ov.y; ob[2] = (__bf16)ov.z; ob[3] = (__bf16)ov.w;
  *(bf16x4*)(xbo + base) = ob;
}

extern "C" void kernel_launch(void* const* d_in, const int* in_sizes, int n_in,
                              void* d_out, int out_size, void* d_ws, size_t ws_size,
                              hipStream_t stream) {
  (void)in_sizes; (void)n_in; (void)out_size; (void)ws_size;
  const float* query = (const float*)d_in[0];
  const float* key   = (const float*)d_in[1];
  const int* qmask   = (const int*)d_in[2];
  const int* kmask   = (const int*)d_in[3];
  const float* Wq = (const float*)d_in[4];
  const float* bq = (const float*)d_in[5];
  const float* Wk = (const float*)d_in[6];
  const float* bk = (const float*)d_in[7];
  const float* Wv = (const float*)d_in[8];
  const float* bv = (const float*)d_in[9];
  const float* Wo = (const float*)d_in[10];
  const float* bo = (const float*)d_in[11];
  const float* ln1g = (const float*)d_in[12];
  const float* ln1b = (const float*)d_in[13];
  const float* fw1 = (const float*)d_in[14];
  const float* fb1 = (const float*)d_in[15];
  const float* fw2 = (const float*)d_in[16];
  const float* fb2 = (const float*)d_in[17];
  const float* ln2g = (const float*)d_in[18];
  const float* ln2b = (const float*)d_in[19];

  char* ws = (char*)d_ws;
  size_t off = 0;
  auto carve = [&](size_t bytes) -> void* {
    void* p = ws + off;
    off += (bytes + 255) & ~(size_t)255;
    return p;
  };
  float* x_f    = (float*)carve((size_t)Mc * Dc * 4);
  float* tmp_f  = (float*)carve((size_t)2 * Mc * Dc * 4);  // split-K partials z=0,1
  __bf16* x_b   = (__bf16*)carve((size_t)Mc * Dc * 2);
  __bf16* key_b = (__bf16*)carve((size_t)Mc * Dc * 2);
  __bf16* at_b  = (__bf16*)carve((size_t)Mc * Dc * 2);
  __bf16* h_b   = (__bf16*)carve((size_t)Mc * FFc * 2);
  __bf16* k_all = (__bf16*)carve((size_t)LAYERS * Mc * Dc * 2);
  __bf16* vt_all= (__bf16*)carve((size_t)LAYERS * Mc * Dc * 2);
  __bf16* wq_b  = (__bf16*)carve((size_t)LAYERS * Dc * Dc * 2);
  __bf16* wkv_b = (__bf16*)carve((size_t)LAYERS * 2 * Dc * Dc * 2);
  __bf16* wo_b  = (__bf16*)carve((size_t)LAYERS * Dc * Dc * 2);
  __bf16* w1_b  = (__bf16*)carve((size_t)LAYERS * FFc * Dc * 2);
  __bf16* w2_b  = (__bf16*)carve((size_t)LAYERS * Dc * FFc * 2);
  float* ml_f   = (float*)carve((size_t)NS * Bc * Hc * Sc * 4 * 2);  // m,l partials
  float* kb_f   = (float*)carve((size_t)Bc * Sc * 4);                // key bias

  __bf16* opart_b = h_b;  // reuse (free during attention)
  float* mpart_f = ml_f;
  float* lpart_f = ml_f + (size_t)NS * Bc * Hc * Sc;
  float* tmp2_f = tmp_f + (size_t)Mc * Dc;

  // fused conversions: 19922944 elements / 4 per thread / 256 per block
  cvt_all<<<19456, 256, 0, stream>>>(Wq, Wo, fw1, fw2, query, key,
                                     wq_b, wo_b, w1_b, w2_b, x_b, key_b, x_f);
  cvt_kv_kernel<<<LAYERS * 2 * Dc * Dc / 1024, 256, 0, stream>>>(Wk, Wv, wkv_b);
  kbias_kernel<<<Bc * Sc / 256, 256, 0, stream>>>(kmask, kb_f, Bc * Sc);

  const dim3 blk(256);
  const dim3 gOP(Dc / 64, Mc / 64, 2);              // O-proj split-K, 1024 blocks
  const dim3 gFF2(Dc / 64, Mc / 64, 2);             // FFN2 split-K, 1024 blocks
  const dim3 gKV(LAYERS * 2 * Dc / 128, Mc / 64);   // 48 x 64 = 3072 blocks
  const dim3 gFF1(FFc / 128, Mc / 64);              // 64x128 tiles, 1024 blocks
  const dim3 gAttn(Sc / 64 * Bc * Hc * NS);         // 1024, 1-D + XCD swizzle
  const dim3 gComb(Bc * Hc * Sc * 8 / 256);         // 1024, 8 elems/thread
  const dim3 gLN(Mc / 2);                           // 2 rows per block

  // all layers' K/V projections in one batched GEMM (depends only on `key`)
  gemm_bt<64, 128, 2, 4, 6><<<gKV, blk, 0, stream>>>(
      key_b, wkv_b, bk, bv, nullptr, k_all, vt_all, 1.0f,
      Mc, LAYERS * 2 * Dc, Dc, Dc);

  for (int i = 0; i < LAYERS; ++i) {
    const __bf16* wq_i = wq_b + (size_t)i * Dc * Dc;
    const __bf16* wo_i = wo_b + (size_t)i * Dc * Dc;
    const __bf16* w1_i = w1_b + (size_t)i * FFc * Dc;
    const __bf16* w2_i = w2_b + (size_t)i * Dc * FFc;
    const __bf16* k_i  = k_all + (size_t)i * Mc * Dc;
    const __bf16* vt_i = vt_all + (size_t)i * Mc * Dc;

    attn_kernel<<<gAttn, blk, 0, stream>>>(x_b, wq_i, bq + i * Dc, k_i, vt_i,
                                           kb_f, opart_b, mpart_f, lpart_f);
    attn_combine<<<gComb, blk, 0, stream>>>(opart_b, mpart_f, lpart_f, at_b);
    gemm_bt<64, 64, 2, 2, 0><<<gOP, blk, 0, stream>>>(
        at_b, wo_i, bo + i * Dc, nullptr, tmp_f, nullptr, nullptr, 1.0f,
        Mc, Dc, Dc / 2, Dc);
    add_ln_kernel<<<gLN, blk, 0, stream>>>(tmp_f, tmp2_f, qmask, x_f,
                                           ln1g + i * Dc, ln1b + i * Dc, x_f, x_b);
    gemm_bt<64, 128, 2, 4, 4><<<gFF1, blk, 0, stream>>>(
        x_b, w1_i, fb1 + i * FFc, nullptr, nullptr, h_b, nullptr, 1.0f,
        Mc, FFc, Dc, Dc);
    gemm_bt<64, 64, 2, 2, 0><<<gFF2, blk, 0, stream>>>(
        h_b, w2_i, fb2 + i * Dc, nullptr, tmp_f, nullptr, nullptr, 1.0f,
        Mc, Dc, FFc / 2, FFc);
    add_ln_kernel<<<gLN, blk, 0, stream>>>(tmp_f, tmp2_f, qmask, x_f,
                                           ln2g + i * Dc, ln2b + i * Dc, x_f, x_b);
  }
  hipMemcpyAsync(d_out, x_f, (size_t)Mc * Dc * 4, hipMemcpyDeviceToDevice, stream);
}

// Round 13
// 887.087 us; speedup vs baseline: 1.0335x; 1.0335x over previous
//
#include <hip/hip_runtime.h>
#include <stdint.h>

constexpr int LAYERS = 6;
constexpr int Bc = 2, Sc = 2048, Dc = 512, Hc = 8, DHc = 64, FFc = 2048;
constexpr int Mc = Bc * Sc;  // 4096
constexpr int NS = 2;        // attention K-splits
constexpr int KCHUNK = Sc / NS;  // 1024

typedef __attribute__((ext_vector_type(8))) __bf16 bf16x8;
typedef __attribute__((ext_vector_type(4))) __bf16 bf16x4;
typedef __attribute__((ext_vector_type(4))) float f32x4;

__device__ __forceinline__ void async_ld16(const void* g, void* lds) {
  __builtin_amdgcn_global_load_lds(
      (const __attribute__((address_space(1))) uint32_t*)g,
      (__attribute__((address_space(3))) uint32_t*)lds, 16, 0, 0);
}

// ---------------- fused fp32 -> bf16 conversion of all inputs ----------------
// Segments: Wq | Wo | fw1 | fw2 | query(+f32 copy) | key
__global__ __launch_bounds__(256) void cvt_all(
    const float* __restrict__ Wq, const float* __restrict__ Wo,
    const float* __restrict__ fw1, const float* __restrict__ fw2,
    const float* __restrict__ query, const float* __restrict__ key,
    __bf16* __restrict__ wq_b, __bf16* __restrict__ wo_b,
    __bf16* __restrict__ w1_b, __bf16* __restrict__ w2_b,
    __bf16* __restrict__ x_b, __bf16* __restrict__ key_b,
    float* __restrict__ x_f) {
  size_t i = ((size_t)blockIdx.x * 256 + threadIdx.x) * 4;
  constexpr size_t nW = (size_t)LAYERS * Dc * Dc;   // 1572864
  constexpr size_t nF = (size_t)LAYERS * FFc * Dc;  // 6291456
  constexpr size_t nX = (size_t)Mc * Dc;            // 2097152
  const float* src;
  __bf16* dst;
  float* fdst = nullptr;
  if (i < nW) { src = Wq + i; dst = wq_b + i; }
  else if (i < 2 * nW) { size_t j = i - nW; src = Wo + j; dst = wo_b + j; }
  else if (i < 2 * nW + nF) { size_t j = i - 2 * nW; src = fw1 + j; dst = w1_b + j; }
  else if (i < 2 * nW + 2 * nF) { size_t j = i - 2 * nW - nF; src = fw2 + j; dst = w2_b + j; }
  else if (i < 2 * nW + 2 * nF + nX) {
    size_t j = i - 2 * nW - 2 * nF;
    src = query + j; dst = x_b + j; fdst = x_f + j;
  } else {
    size_t j = i - 2 * nW - 2 * nF - nX;
    src = key + j; dst = key_b + j;
  }
  const float4 v = *(const float4*)src;
  bf16x4 o;
  o[0] = (__bf16)v.x; o[1] = (__bf16)v.y; o[2] = (__bf16)v.z; o[3] = (__bf16)v.w;
  *(bf16x4*)dst = o;
  if (fdst) *(float4*)fdst = v;
}

// interleave all layers' Wk,Wv into one bf16 buffer [L][2][D][D]
__global__ __launch_bounds__(256) void cvt_kv_kernel(const float* __restrict__ Wk,
                                                     const float* __restrict__ Wv,
                                                     __bf16* __restrict__ out) {
  size_t i = ((size_t)blockIdx.x * 256 + threadIdx.x) * 4;
  int n = (int)(i / ((size_t)Dc * Dc));  // lyr*2 + p
  int lyr = n >> 1, p = n & 1;
  size_t idx = i - (size_t)n * Dc * Dc;
  const float* src = (p ? Wv : Wk) + (size_t)lyr * Dc * Dc + idx;
  const float4 v = *(const float4*)src;
  bf16x4 o;
  o[0] = (__bf16)v.x; o[1] = (__bf16)v.y; o[2] = (__bf16)v.z; o[3] = (__bf16)v.w;
  *(bf16x4*)(out + i) = o;
}

// key mask -> additive bias
__global__ __launch_bounds__(256) void kbias_kernel(const int* __restrict__ km,
                                                    float* __restrict__ kb, int n) {
  int i = blockIdx.x * 256 + threadIdx.x;
  if (i < n) kb[i] = km[i] ? 0.f : -1e30f;
}

// ---------------- GEMM: C[M,N] = A[M,K] @ W[N,K]^T + bias, fused epilogues ----
// BK=64, 2-phase double-buffered LDS, both-sides XOR swizzle (slot ^ (row&7)).
// Split-K via blockIdx.z: K = per-block chunk, Kstride = full row stride.
// EPI: 0 = f32 row-major partial (outf + z*M*N), bias at z==0
//      1 = bf16 split-head [B,H,S,DH], value *= scale    (Q projection)
//      4 = bf16 row-major, leaky-relu(0.01)              (FFN1)
//      6 = batched KV: N = L*1024; K -> outb [L,B,H,S,DH] via LDS transpose;
//          V -> outb2 [L,B,H,DH,S] via LDS transpose; both coalesced stores
template <int BM, int BN, int WM, int WN, int EPI>
__global__ __launch_bounds__(256) void gemm_bt(
    const __bf16* __restrict__ A, const __bf16* __restrict__ W,
    const float* __restrict__ bias, const float* __restrict__ bias2,
    float* __restrict__ outf, __bf16* __restrict__ outb,
    __bf16* __restrict__ outb2, float scale,
    int M, int N, int K, int Kstride) {
  constexpr int BK = 64;
  __shared__ __bf16 As[2][BM * BK];
  __shared__ __bf16 Bs[2][BN * BK];
  const int tid = threadIdx.x;
  const int l15 = tid & 15;
  const int lg = (tid & 63) >> 4;
  const int w = tid >> 6;
  const int wm = w >> 1, wn = w & 1;
  const int tm = blockIdx.y * BM;
  const int tn = blockIdx.x * BN;
  const int z = blockIdx.z;
  const __bf16* Ap = A + (size_t)tm * Kstride + (size_t)z * K;
  const __bf16* Wp = W + (size_t)tn * Kstride + (size_t)z * K;
  f32x4 acc[WM][WN] = {};

  auto stage = [&](int k0, int bf) {
#pragma unroll
    for (int c = 0; c < BM * 8 / 256; ++c) {
      int cc = c * 256 + tid;
      int r = cc >> 3, s = cc & 7;
      int ss = s ^ (r & 7);  // inverse-swizzled source slot
      async_ld16(Ap + (size_t)r * Kstride + k0 + ss * 8, &As[bf][cc * 8]);
    }
#pragma unroll
    for (int c = 0; c < BN * 8 / 256; ++c) {
      int cc = c * 256 + tid;
      int r = cc >> 3, s = cc & 7;
      int ss = s ^ (r & 7);
      async_ld16(Wp + (size_t)r * Kstride + k0 + ss * 8, &Bs[bf][cc * 8]);
    }
  };

  const int nk = K / BK;
  stage(0, 0);
  __syncthreads();
  int buf = 0;
  for (int t = 0; t < nk; ++t) {
    if (t + 1 < nk) stage((t + 1) * BK, buf ^ 1);
    bf16x8 af[WM][2], bfr[WN][2];
#pragma unroll
    for (int i = 0; i < WM; ++i) {
      int row = wm * WM * 16 + i * 16 + l15;
#pragma unroll
      for (int kf = 0; kf < 2; ++kf)
        af[i][kf] = *(const bf16x8*)&As[buf][row * 64 + (((kf * 4 + lg) ^ (row & 7)) * 8)];
    }
#pragma unroll
    for (int j = 0; j < WN; ++j) {
      int row = wn * WN * 16 + j * 16 + l15;
#pragma unroll
      for (int kf = 0; kf < 2; ++kf)
        bfr[j][kf] = *(const bf16x8*)&Bs[buf][row * 64 + (((kf * 4 + lg) ^ (row & 7)) * 8)];
    }
#pragma unroll
    for (int kf = 0; kf < 2; ++kf)
#pragma unroll
      for (int i = 0; i < WM; ++i)
#pragma unroll
        for (int j = 0; j < WN; ++j)
          acc[i][j] = __builtin_amdgcn_mfma_f32_16x16x32_bf16(af[i][kf], bfr[j][kf], acc[i][j], 0, 0, 0);
    __syncthreads();
    buf ^= 1;
  }

  if constexpr (EPI == 6) {
    const bool isV = ((tn & 1023) >= 512);
    const int lyr = tn >> 10;
    const int b = tm >> 11;
    const int sbase = tm & (Sc - 1);
    if (isV) {
      // V half: transpose 64(s) x 128(d) tile through LDS, coalesced stores.
      __bf16* T = (__bf16*)&As[0][0];  // [128 d][64 s], 16B-slot XOR swizzle
#pragma unroll
      for (int i = 0; i < WM; ++i) {
#pragma unroll
        for (int j = 0; j < WN; ++j) {
          const int d = wn * WN * 16 + j * 16 + l15;   // 0..127
          const int dg = (tn & 511) + d;               // 0..511 within layer V
          const float bv = bias2[lyr * 512 + dg];
          const int s0 = wm * WM * 16 + i * 16 + lg * 4;
          bf16x4 pk;
#pragma unroll
          for (int r = 0; r < 4; ++r) pk[r] = (__bf16)(acc[i][j][r] + bv);
          const int slot = (s0 >> 3) ^ (d & 7);
          *(bf16x4*)&T[d * 64 + slot * 8 + (s0 & 7)] = pk;
        }
      }
      __syncthreads();
      const int rr = tid >> 3;   // 0..31
      const int c8 = tid & 7;    // s-slot
#pragma unroll
      for (int pass = 0; pass < 4; ++pass) {
        const int d = pass * 32 + rr;
        const int slot = c8 ^ (d & 7);
        bf16x8 v8 = *(const bf16x8*)&T[d * 64 + slot * 8];
        const int dg = (tn & 511) + d;
        const int h = dg >> 6, dh = dg & 63;
        *(bf16x8*)&outb2[((((size_t)(lyr * Bc + b) * Hc + h)) * DHc + dh) * Sc +
                         sbase + c8 * 8] = v8;
      }
    } else {
      // K half: transpose-free but store-coalesced via LDS [64 s][128 d].
      __bf16* T = (__bf16*)&As[0][0];  // 64*128 = 8192 elems = all of As
#pragma unroll
      for (int i = 0; i < WM; ++i) {
#pragma unroll
        for (int j = 0; j < WN; ++j) {
          const int d = wn * WN * 16 + j * 16 + l15;   // 0..127
          const int dg = (tn & 511) + d;
          const float bv = bias[lyr * 512 + dg];
          const int slot = (d >> 3) ^ 0;               // base slot; swizzle per s below
#pragma unroll
          for (int r = 0; r < 4; ++r) {
            const int s = wm * WM * 16 + i * 16 + lg * 4 + r;  // 0..63
            const int sl = (d >> 3) ^ (s & 15);
            T[s * 128 + sl * 8 + (d & 7)] = (__bf16)(acc[i][j][r] + bv);
          }
          (void)slot;
        }
      }
      __syncthreads();
#pragma unroll
      for (int pass = 0; pass < 4; ++pass) {
        const int id = pass * 256 + tid;   // 0..1023
        const int s = id >> 4;             // 0..63
        const int g = id & 15;             // logical d-group (8 elems)
        const int sl = g ^ (s & 15);
        bf16x8 v8 = *(const bf16x8*)&T[s * 128 + sl * 8];
        const int dg0 = (tn & 511) + g * 8;
        const int h = dg0 >> 6, dh = dg0 & 63;
        *(bf16x8*)&outb[((((size_t)(lyr * Bc + b) * Hc + h)) * Sc + sbase + s) * DHc + dh] = v8;
      }
    }
    return;
  }

#pragma unroll
  for (int i = 0; i < WM; ++i) {
#pragma unroll
    for (int j = 0; j < WN; ++j) {
      const int n = tn + wn * WN * 16 + j * 16 + l15;
      float bv;
      if constexpr (EPI == 0) {
        bv = (z == 0) ? bias[n] : 0.f;
      } else {
        bv = bias[n];
      }
#pragma unroll
      for (int r = 0; r < 4; ++r) {
        const int m = tm + wm * WM * 16 + i * 16 + lg * 4 + r;
        float v = acc[i][j][r] + bv;
        if constexpr (EPI == 0) {
          outf[(size_t)z * M * N + (size_t)m * N + n] = v;
        } else if constexpr (EPI == 1) {
          int b = m >> 11, s = m & (Sc - 1);
          int h = n >> 6, dh = n & 63;
          outb[(((size_t)(b * Hc + h)) * Sc + s) * DHc + dh] = (__bf16)(v * scale);
        } else if constexpr (EPI == 4) {
          float lv = v > 0.f ? v : 0.01f * v;
          outb[(size_t)m * N + n] = (__bf16)lv;
        }
      }
    }
  }
}

// ---------------- flash attention with K-split, swapped QK^T ----------------
// Computes S = mfma(K, Q) so each lane holds P[k-chunk][q=lane&15]: row-max is
// 15 local fmax + 2 shfl_xor; P never round-trips LDS (in-register exchange to
// the PV A-fragment via bpermute). K,V staged in LDS (double-buffered,
// swizzled). XCD-chunked block swizzle keeps per-XCD K/V set L2-resident.
__global__ __launch_bounds__(256, 5) void attn_kernel(
    const __bf16* __restrict__ q, const __bf16* __restrict__ k,
    const __bf16* __restrict__ vt, const float* __restrict__ kb,
    __bf16* __restrict__ Opart, float* __restrict__ mpart,
    float* __restrict__ lpart) {
  const int bid = blockIdx.x;
  const int o = (bid & 7) * 128 + (bid >> 3);  // bijective (1024 = 8*128)
  const int qb = o & 31;
  const int p = o >> 5;      // 0..31 = bh*NS + z
  const int bh = p >> 1;
  const int z = p & 1;
  const int b = bh >> 3;
  const int w = threadIdx.x >> 6;
  const int l = threadIdx.x & 63;
  const int l15 = l & 15;
  const int lg = l >> 4;
  const int tid = threadIdx.x;
  const int qbase = qb * 64 + w * 16;
  const int k0 = z * KCHUNK;

  const __bf16* qp = q + ((size_t)bh * Sc + qbase) * DHc;
  const __bf16* kp = k + (size_t)bh * Sc * DHc;
  const __bf16* vp = vt + (size_t)bh * DHc * Sc;
  const float* kbp = kb + (size_t)b * Sc;

  bf16x8 qf[2];
  qf[0] = *(const bf16x8*)(qp + l15 * DHc + lg * 8);
  qf[1] = *(const bf16x8*)(qp + l15 * DHc + 32 + lg * 8);

  bf16x8 onesf;
#pragma unroll
  for (int i = 0; i < 8; ++i) onesf[i] = (__bf16)1.0f;

  f32x4 oacc[4] = {};
  f32x4 lacc = {};
  float mr = -1e30f;  // running max for q = l15 (converged across lane groups)

  __shared__ __bf16 Ks[2][4096];
  __shared__ __bf16 Vs[2][4096];

  auto stage = [&](int t, int bf) {
    const int kt = k0 + t * 64;
#pragma unroll
    for (int ii = 0; ii < 2; ++ii) {
      int i = ii * 256 + tid;          // 16B slot id, 0..511
      int r = i >> 3;                  // row 0..63
      int bsrc = (i & 7) ^ (r & 7);    // inverse-swizzled source slot
      async_ld16(kp + (size_t)(kt + r) * DHc + bsrc * 8, &Ks[bf][i * 8]);
      async_ld16(vp + (size_t)r * Sc + kt + bsrc * 8, &Vs[bf][i * 8]);
    }
  };

  stage(0, 0);
  // tile-0 mask bias
  float4 mb4[4];
#pragma unroll
  for (int cb = 0; cb < 4; ++cb)
    mb4[cb] = *(const float4*)&kbp[k0 + cb * 16 + lg * 4];
  __syncthreads();

  constexpr int NT = KCHUNK / 64;
  int buf = 0;
  for (int t = 0; t < NT; ++t) {
    const int kt = k0 + t * 64;
    if (t + 1 < NT) stage(t + 1, buf ^ 1);
    // prefetch next tile's mask bias early (consumed next iteration)
    float4 mbn4[4];
    if (t + 1 < NT) {
#pragma unroll
      for (int cb = 0; cb < 4; ++cb)
        mbn4[cb] = *(const float4*)&kbp[kt + 64 + cb * 16 + lg * 4];
    }

    // ---- swapped QK^T: S[k][q], lane holds k=cb*16+lg*4+r, q=l15 ----
    f32x4 sacc[4] = {};
    __builtin_amdgcn_s_setprio(1);
#pragma unroll
    for (int kf = 0; kf < 2; ++kf) {
#pragma unroll
      for (int cb = 0; cb < 4; ++cb) {
        int row = cb * 16 + l15;
        bf16x8 kfr = *(const bf16x8*)&Ks[buf][row * 64 + (((kf * 4 + lg) ^ (row & 7)) * 8)];
        sacc[cb] = __builtin_amdgcn_mfma_f32_16x16x32_bf16(kfr, qf[kf], sacc[cb], 0, 0, 0);
      }
    }
    __builtin_amdgcn_s_setprio(0);
    sacc[0][0] += mb4[0].x; sacc[0][1] += mb4[0].y; sacc[0][2] += mb4[0].z; sacc[0][3] += mb4[0].w;
    sacc[1][0] += mb4[1].x; sacc[1][1] += mb4[1].y; sacc[1][2] += mb4[1].z; sacc[1][3] += mb4[1].w;
    sacc[2][0] += mb4[2].x; sacc[2][1] += mb4[2].y; sacc[2][2] += mb4[2].z; sacc[2][3] += mb4[2].w;
    sacc[3][0] += mb4[3].x; sacc[3][1] += mb4[3].y; sacc[3][2] += mb4[3].z; sacc[3][3] += mb4[3].w;

    // ---- row max: 15 local fmax + 2 shfl_xor (lanes with same l15) ----
    float mx = sacc[0][0];
#pragma unroll
    for (int cb = 0; cb < 4; ++cb)
#pragma unroll
      for (int r = 0; r < 4; ++r) mx = fmaxf(mx, sacc[cb][r]);
    mx = fmaxf(mx, __shfl_xor(mx, 16, 64));
    mx = fmaxf(mx, __shfl_xor(mx, 32, 64));

    if (__any(mx > mr + 8.f)) {   // defer-max: rare rescale
      float mn = fmaxf(mr, mx);
      float f = __expf(mr - mn);
      mr = mn;
      // redistribute f (held at lane l15=q) to output layout q = lg*4+j
      float fj[4];
#pragma unroll
      for (int j = 0; j < 4; ++j) fj[j] = __shfl(f, lg * 4 + j, 64);
#pragma unroll
      for (int j = 0; j < 4; ++j) lacc[j] *= fj[j];
#pragma unroll
      for (int db = 0; db < 4; ++db)
#pragma unroll
        for (int j = 0; j < 4; ++j) oacc[db][j] *= fj[j];
    }

    // ---- P = exp(S - m), pack to bf16 words pw[cb][w2] ----
    unsigned pw[4][2];
#pragma unroll
    for (int cb = 0; cb < 4; ++cb) {
#pragma unroll
      for (int w2 = 0; w2 < 2; ++w2) {
        union { __bf16 h[2]; unsigned u; } cu;
        cu.h[0] = (__bf16)__expf(sacc[cb][2 * w2] - mr);
        cu.h[1] = (__bf16)__expf(sacc[cb][2 * w2 + 1] - mr);
        pw[cb][w2] = cu.u;
      }
    }

    // ---- in-register exchange: build PV A-fragment P[q=l15][k=kf*32+lg*8+e]
    const int srcA = ((lg & 1) * 2) * 16 + l15;
    const int srcB = srcA + 16;
    const bool hi = (lg >> 1) & 1;
#pragma unroll
    for (int kf = 0; kf < 2; ++kf) {
      unsigned t0a = __shfl((int)pw[kf * 2][0], srcA, 64);
      unsigned t0b = __shfl((int)pw[kf * 2 + 1][0], srcA, 64);
      unsigned t1a = __shfl((int)pw[kf * 2][1], srcA, 64);
      unsigned t1b = __shfl((int)pw[kf * 2 + 1][1], srcA, 64);
      unsigned t2a = __shfl((int)pw[kf * 2][0], srcB, 64);
      unsigned t2b = __shfl((int)pw[kf * 2 + 1][0], srcB, 64);
      unsigned t3a = __shfl((int)pw[kf * 2][1], srcB, 64);
      unsigned t3b = __shfl((int)pw[kf * 2 + 1][1], srcB, 64);
      union { unsigned u[4]; bf16x8 v; } pa;
      pa.u[0] = hi ? t0b : t0a;
      pa.u[1] = hi ? t1b : t1a;
      pa.u[2] = hi ? t2b : t2a;
      pa.u[3] = hi ? t3b : t3a;
      __builtin_amdgcn_s_setprio(1);
      lacc = __builtin_amdgcn_mfma_f32_16x16x32_bf16(pa.v, onesf, lacc, 0, 0, 0);
#pragma unroll
      for (int db = 0; db < 4; ++db) {
        int row = db * 16 + l15;
        bf16x8 vf = *(const bf16x8*)&Vs[buf][row * 64 + (((kf * 4 + lg) ^ (row & 7)) * 8)];
        oacc[db] = __builtin_amdgcn_mfma_f32_16x16x32_bf16(pa.v, vf, oacc[db], 0, 0, 0);
      }
      __builtin_amdgcn_s_setprio(0);
    }
    if (t + 1 < NT) {
#pragma unroll
      for (int cb = 0; cb < 4; ++cb) mb4[cb] = mbn4[cb];
    }
    __syncthreads();   // drains stage(t+1) vmem writes + protects buf reuse
    buf ^= 1;
  }

  // ---- write unnormalized partial ----
  const size_t obase = (((size_t)(z * Bc * Hc + bh)) * Sc + qbase) * DHc;
#pragma unroll
  for (int db = 0; db < 4; ++db)
#pragma unroll
    for (int j = 0; j < 4; ++j)
      Opart[obase + (size_t)(lg * 4 + j) * DHc + db * 16 + l15] = (__bf16)oacc[db][j];
  const int row0 = (z * Bc * Hc + bh) * Sc + qbase;
  if (lg == 0) mpart[row0 + l15] = mr;      // m held at lane l15 = q
  if (l15 == 0) {
#pragma unroll
    for (int j = 0; j < 4; ++j) lpart[row0 + lg * 4 + j] = lacc[j];
  }
}

// ---------------- combine split partials -> bf16 [B,S,D] (vectorized) -------
__global__ __launch_bounds__(256) void attn_combine(
    const __bf16* __restrict__ Opart, const float* __restrict__ mpart,
    const float* __restrict__ lpart, __bf16* __restrict__ out) {
  int t = blockIdx.x * 256 + threadIdx.x;  // over BH*S*8 (8 elems per thread)
  int g = t & 7;
  int row = t >> 3;          // bh*Sc + s
  int bh = row >> 11, s = row & (Sc - 1);
  constexpr int RSTRIDE = Bc * Hc * Sc;  // rows per split
  float m0 = mpart[row], m1 = mpart[RSTRIDE + row];
  float l0 = lpart[row], l1 = lpart[RSTRIDE + row];
  float M = fmaxf(m0, m1);
  float e0 = __expf(m0 - M), e1 = __expf(m1 - M);
  float inv = 1.0f / (e0 * l0 + e1 * l1);
  bf16x8 o0 = *(const bf16x8*)&Opart[(size_t)row * DHc + g * 8];
  bf16x8 o1 = *(const bf16x8*)&Opart[((size_t)RSTRIDE + row) * DHc + g * 8];
  bf16x8 r;
#pragma unroll
  for (int e = 0; e < 8; ++e)
    r[e] = (__bf16)((e0 * (float)o0[e] + e1 * (float)o1[e]) * inv);
  int b = bh >> 3, h = bh & 7;
  *(bf16x8*)&out[(((size_t)b * Sc + s)) * Dc + h * DHc + g * 8] = r;
}

// ---------------- residual add + LayerNorm (vectorized, 2 rows/block) -------
// x_out = LN((res + res2) * mask + xin) * g + b ; writes fp32 and bf16.
__global__ __launch_bounds__(256) void add_ln_kernel(
    const float* __restrict__ res, const float* __restrict__ res2,
    const int* __restrict__ rmask, const float* __restrict__ xin,
    const float* __restrict__ g, const float* __restrict__ bb,
    float* __restrict__ xo, __bf16* __restrict__ xbo) {
  const int tid = threadIdx.x;
  const int rl = tid >> 7;                 // row within pair (0/1)
  const int row = blockIdx.x * 2 + rl;
  const int ci = (tid & 127) * 4;          // column start
  const size_t base = (size_t)row * Dc + ci;
  const float4 a = *(const float4*)(res + base);
  const float4 a2 = *(const float4*)(res2 + base);
  const float4 xv = *(const float4*)(xin + base);
  const float mfac = (float)rmask[row];
  float4 v;
  v.x = (a.x + a2.x) * mfac + xv.x;
  v.y = (a.y + a2.y) * mfac + xv.y;
  v.z = (a.z + a2.z) * mfac + xv.z;
  v.w = (a.w + a2.w) * mfac + xv.w;
  float s = v.x + v.y + v.z + v.w;
#pragma unroll
  for (int d = 1; d < 64; d <<= 1) s += __shfl_xor(s, d, 64);
  __shared__ float red[4], red2[4];
  if ((tid & 63) == 0) red[tid >> 6] = s;
  __syncthreads();
  float mean = (red[rl * 2] + red[rl * 2 + 1]) * (1.0f / Dc);
  float4 dv;
  dv.x = v.x - mean; dv.y = v.y - mean; dv.z = v.z - mean; dv.w = v.w - mean;
  float qq = dv.x * dv.x + dv.y * dv.y + dv.z * dv.z + dv.w * dv.w;
#pragma unroll
  for (int d = 1; d < 64; d <<= 1) qq += __shfl_xor(qq, d, 64);
  if ((tid & 63) == 0) red2[tid >> 6] = qq;
  __syncthreads();
  float var = (red2[rl * 2] + red2[rl * 2 + 1]) * (1.0f / Dc);
  float rs = rsqrtf(var + 1e-5f);
  const float4 gv = *(const float4*)(g + ci);
  const float4 bv = *(const float4*)(bb + ci);
  float4 ov;
  ov.x = dv.x * rs * gv.x + bv.x;
  ov.y = dv.y * rs * gv.y + bv.y;
  ov.z = dv.z * rs * gv.z + bv.z;
  ov.w = dv.w * rs * gv.w + bv.w;
  *(float4*)(xo + base) = ov;
  bf16x4 ob;
  ob[0] = (__bf16)ov.x; ob[1] = (__bf16)ov.y; ob[2] = (__bf16)ov.z; ob[3] = (__bf16)ov.w;
  *(bf16x4*)(xbo + base) = ob;
}

extern "C" void kernel_launch(void* const* d_in, const int* in_sizes, int n_in,
                              void* d_out, int out_size, void* d_ws, size_t ws_size,
                              hipStream_t stream) {
  (void)in_sizes; (void)n_in; (void)out_size; (void)ws_size;
  const float* query = (const float*)d_in[0];
  const float* key   = (const float*)d_in[1];
  const int* qmask   = (const int*)d_in[2];
  const int* kmask   = (const int*)d_in[3];
  const float* Wq = (const float*)d_in[4];
  const float* bq = (const float*)d_in[5];
  const float* Wk = (const float*)d_in[6];
  const float* bk = (const float*)d_in[7];
  const float* Wv = (const float*)d_in[8];
  const float* bv = (const float*)d_in[9];
  const float* Wo = (const float*)d_in[10];
  const float* bo = (const float*)d_in[11];
  const float* ln1g = (const float*)d_in[12];
  const float* ln1b = (const float*)d_in[13];
  const float* fw1 = (const float*)d_in[14];
  const float* fb1 = (const float*)d_in[15];
  const float* fw2 = (const float*)d_in[16];
  const float* fb2 = (const float*)d_in[17];
  const float* ln2g = (const float*)d_in[18];
  const float* ln2b = (const float*)d_in[19];

  char* ws = (char*)d_ws;
  size_t off = 0;
  auto carve = [&](size_t bytes) -> void* {
    void* p = ws + off;
    off += (bytes + 255) & ~(size_t)255;
    return p;
  };
  float* x_f    = (float*)carve((size_t)Mc * Dc * 4);
  float* tmp_f  = (float*)carve((size_t)2 * Mc * Dc * 4);  // split-K partials z=0,1
  __bf16* x_b   = (__bf16*)carve((size_t)Mc * Dc * 2);
  __bf16* key_b = (__bf16*)carve((size_t)Mc * Dc * 2);
  __bf16* q_b   = (__bf16*)carve((size_t)Mc * Dc * 2);
  __bf16* at_b  = (__bf16*)carve((size_t)Mc * Dc * 2);
  __bf16* h_b   = (__bf16*)carve((size_t)Mc * FFc * 2);
  __bf16* k_all = (__bf16*)carve((size_t)LAYERS * Mc * Dc * 2);
  __bf16* vt_all= (__bf16*)carve((size_t)LAYERS * Mc * Dc * 2);
  __bf16* wq_b  = (__bf16*)carve((size_t)LAYERS * Dc * Dc * 2);
  __bf16* wkv_b = (__bf16*)carve((size_t)LAYERS * 2 * Dc * Dc * 2);
  __bf16* wo_b  = (__bf16*)carve((size_t)LAYERS * Dc * Dc * 2);
  __bf16* w1_b  = (__bf16*)carve((size_t)LAYERS * FFc * Dc * 2);
  __bf16* w2_b  = (__bf16*)carve((size_t)LAYERS * Dc * FFc * 2);
  float* ml_f   = (float*)carve((size_t)NS * Bc * Hc * Sc * 4 * 2);  // m,l partials
  float* kb_f   = (float*)carve((size_t)Bc * Sc * 4);                // key bias

  __bf16* opart_b = h_b;  // reuse (free during attention)
  float* mpart_f = ml_f;
  float* lpart_f = ml_f + (size_t)NS * Bc * Hc * Sc;
  float* tmp2_f = tmp_f + (size_t)Mc * Dc;

  // fused conversions: 19922944 elements / 4 per thread / 256 per block
  cvt_all<<<19456, 256, 0, stream>>>(Wq, Wo, fw1, fw2, query, key,
                                     wq_b, wo_b, w1_b, w2_b, x_b, key_b, x_f);
  cvt_kv_kernel<<<LAYERS * 2 * Dc * Dc / 1024, 256, 0, stream>>>(Wk, Wv, wkv_b);
  kbias_kernel<<<Bc * Sc / 256, 256, 0, stream>>>(kmask, kb_f, Bc * Sc);

  const dim3 blk(256);
  const dim3 gP64(Dc / 64, Mc / 64);                // 512 blocks (Q proj)
  const dim3 gOP(Dc / 64, Mc / 64, 2);              // O-proj split-K, 1024 blocks
  const dim3 gFF2(Dc / 64, Mc / 64, 2);             // FFN2 split-K, 1024 blocks
  const dim3 gKV(LAYERS * 2 * Dc / 128, Mc / 64);   // 48 x 64 = 3072 blocks
  const dim3 gFF1(FFc / 128, Mc / 64);              // 64x128 tiles, 1024 blocks
  const dim3 gAttn(Sc / 64 * Bc * Hc * NS);         // 1024, 1-D + XCD swizzle
  const dim3 gComb(Bc * Hc * Sc * 8 / 256);         // 1024, 8 elems/thread
  const dim3 gLN(Mc / 2);                           // 2 rows per block

  // all layers' K/V projections in one batched GEMM (depends only on `key`)
  gemm_bt<64, 128, 2, 4, 6><<<gKV, blk, 0, stream>>>(
      key_b, wkv_b, bk, bv, nullptr, k_all, vt_all, 1.0f,
      Mc, LAYERS * 2 * Dc, Dc, Dc);

  for (int i = 0; i < LAYERS; ++i) {
    const __bf16* wq_i = wq_b + (size_t)i * Dc * Dc;
    const __bf16* wo_i = wo_b + (size_t)i * Dc * Dc;
    const __bf16* w1_i = w1_b + (size_t)i * FFc * Dc;
    const __bf16* w2_i = w2_b + (size_t)i * Dc * FFc;
    const __bf16* k_i  = k_all + (size_t)i * Mc * Dc;
    const __bf16* vt_i = vt_all + (size_t)i * Mc * Dc;

    gemm_bt<64, 64, 2, 2, 1><<<gP64, blk, 0, stream>>>(
        x_b, wq_i, bq + i * Dc, nullptr, nullptr, q_b, nullptr, 0.125f,
        Mc, Dc, Dc, Dc);
    attn_kernel<<<gAttn, blk, 0, stream>>>(q_b, k_i, vt_i, kb_f,
                                           opart_b, mpart_f, lpart_f);
    attn_combine<<<gComb, blk, 0, stream>>>(opart_b, mpart_f, lpart_f, at_b);
    gemm_bt<64, 64, 2, 2, 0><<<gOP, blk, 0, stream>>>(
        at_b, wo_i, bo + i * Dc, nullptr, tmp_f, nullptr, nullptr, 1.0f,
        Mc, Dc, Dc / 2, Dc);
    add_ln_kernel<<<gLN, blk, 0, stream>>>(tmp_f, tmp2_f, qmask, x_f,
                                           ln1g + i * Dc, ln1b + i * Dc, x_f, x_b);
    gemm_bt<64, 128, 2, 4, 4><<<gFF1, blk, 0, stream>>>(
        x_b, w1_i, fb1 + i * FFc, nullptr, nullptr, h_b, nullptr, 1.0f,
        Mc, FFc, Dc, Dc);
    gemm_bt<64, 64, 2, 2, 0><<<gFF2, blk, 0, stream>>>(
        h_b, w2_i, fb2 + i * Dc, nullptr, tmp_f, nullptr, nullptr, 1.0f,
        Mc, Dc, FFc / 2, FFc);
    add_ln_kernel<<<gLN, blk, 0, stream>>>(tmp_f, tmp2_f, qmask, x_f,
                                           ln2g + i * Dc, ln2b + i * Dc, x_f, x_b);
  }
  hipMemcpyAsync(d_out, x_f, (size_t)Mc * Dc * 4, hipMemcpyDeviceToDevice, stream);
}

// Round 14
// 835.658 us; speedup vs baseline: 1.0971x; 1.0615x over previous
//
#include <hip/hip_runtime.h>
#include <stdint.h>

constexpr int LAYERS = 6;
constexpr int Bc = 2, Sc = 2048, Dc = 512, Hc = 8, DHc = 64, FFc = 2048;
constexpr int Mc = Bc * Sc;  // 4096
constexpr int NS = 2;        // attention K-splits
constexpr int KCHUNK = Sc / NS;  // 1024

typedef __attribute__((ext_vector_type(8))) __bf16 bf16x8;
typedef __attribute__((ext_vector_type(4))) __bf16 bf16x4;
typedef __attribute__((ext_vector_type(4))) float f32x4;

__device__ __forceinline__ void async_ld16(const void* g, void* lds) {
  __builtin_amdgcn_global_load_lds(
      (const __attribute__((address_space(1))) uint32_t*)g,
      (__attribute__((address_space(3))) uint32_t*)lds, 16, 0, 0);
}

// ---------------- fused fp32 -> bf16 conversion of all inputs ----------------
// Segments: Wq | Wo | fw1 | fw2 | query(+f32 copy) | key
__global__ __launch_bounds__(256) void cvt_all(
    const float* __restrict__ Wq, const float* __restrict__ Wo,
    const float* __restrict__ fw1, const float* __restrict__ fw2,
    const float* __restrict__ query, const float* __restrict__ key,
    __bf16* __restrict__ wq_b, __bf16* __restrict__ wo_b,
    __bf16* __restrict__ w1_b, __bf16* __restrict__ w2_b,
    __bf16* __restrict__ x_b, __bf16* __restrict__ key_b,
    float* __restrict__ x_f) {
  size_t i = ((size_t)blockIdx.x * 256 + threadIdx.x) * 4;
  constexpr size_t nW = (size_t)LAYERS * Dc * Dc;   // 1572864
  constexpr size_t nF = (size_t)LAYERS * FFc * Dc;  // 6291456
  constexpr size_t nX = (size_t)Mc * Dc;            // 2097152
  const float* src;
  __bf16* dst;
  float* fdst = nullptr;
  if (i < nW) { src = Wq + i; dst = wq_b + i; }
  else if (i < 2 * nW) { size_t j = i - nW; src = Wo + j; dst = wo_b + j; }
  else if (i < 2 * nW + nF) { size_t j = i - 2 * nW; src = fw1 + j; dst = w1_b + j; }
  else if (i < 2 * nW + 2 * nF) { size_t j = i - 2 * nW - nF; src = fw2 + j; dst = w2_b + j; }
  else if (i < 2 * nW + 2 * nF + nX) {
    size_t j = i - 2 * nW - 2 * nF;
    src = query + j; dst = x_b + j; fdst = x_f + j;
  } else {
    size_t j = i - 2 * nW - 2 * nF - nX;
    src = key + j; dst = key_b + j;
  }
  const float4 v = *(const float4*)src;
  bf16x4 o;
  o[0] = (__bf16)v.x; o[1] = (__bf16)v.y; o[2] = (__bf16)v.z; o[3] = (__bf16)v.w;
  *(bf16x4*)dst = o;
  if (fdst) *(float4*)fdst = v;
}

// interleave all layers' Wk,Wv into one bf16 buffer [L][2][D][D]
__global__ __launch_bounds__(256) void cvt_kv_kernel(const float* __restrict__ Wk,
                                                     const float* __restrict__ Wv,
                                                     __bf16* __restrict__ out) {
  size_t i = ((size_t)blockIdx.x * 256 + threadIdx.x) * 4;
  int n = (int)(i / ((size_t)Dc * Dc));  // lyr*2 + p
  int lyr = n >> 1, p = n & 1;
  size_t idx = i - (size_t)n * Dc * Dc;
  const float* src = (p ? Wv : Wk) + (size_t)lyr * Dc * Dc + idx;
  const float4 v = *(const float4*)src;
  bf16x4 o;
  o[0] = (__bf16)v.x; o[1] = (__bf16)v.y; o[2] = (__bf16)v.z; o[3] = (__bf16)v.w;
  *(bf16x4*)(out + i) = o;
}

// key mask -> additive bias
__global__ __launch_bounds__(256) void kbias_kernel(const int* __restrict__ km,
                                                    float* __restrict__ kb, int n) {
  int i = blockIdx.x * 256 + threadIdx.x;
  if (i < n) kb[i] = km[i] ? 0.f : -1e30f;
}

// ---------------- GEMM: C[M,N] = A[M,K] @ W[N,K]^T + bias, fused epilogues ----
// BK=64, 2-phase double-buffered LDS, both-sides XOR swizzle (slot ^ (row&7)).
// Split-K via blockIdx.z: K = per-block chunk, Kstride = full row stride.
// EPI: 0 = f32 row-major partial (outf + z*M*N), bias at z==0
//      1 = bf16 split-head [B,H,S,DH], value *= scale    (Q projection)
//      4 = bf16 row-major, leaky-relu(0.01)              (FFN1)
//      6 = batched KV: N = L*1024; K -> outb [L,B,H,S,DH];
//          V -> outb2 [L,B,H,DH,S] via LDS-transposed coalesced stores
template <int BM, int BN, int WM, int WN, int EPI>
__global__ __launch_bounds__(256) void gemm_bt(
    const __bf16* __restrict__ A, const __bf16* __restrict__ W,
    const float* __restrict__ bias, const float* __restrict__ bias2,
    float* __restrict__ outf, __bf16* __restrict__ outb,
    __bf16* __restrict__ outb2, float scale,
    int M, int N, int K, int Kstride) {
  constexpr int BK = 64;
  __shared__ __bf16 As[2][BM * BK];
  __shared__ __bf16 Bs[2][BN * BK];
  const int tid = threadIdx.x;
  const int l15 = tid & 15;
  const int lg = (tid & 63) >> 4;
  const int w = tid >> 6;
  const int wm = w >> 1, wn = w & 1;
  const int tm = blockIdx.y * BM;
  const int tn = blockIdx.x * BN;
  const int z = blockIdx.z;
  const __bf16* Ap = A + (size_t)tm * Kstride + (size_t)z * K;
  const __bf16* Wp = W + (size_t)tn * Kstride + (size_t)z * K;
  f32x4 acc[WM][WN] = {};

  auto stage = [&](int k0, int bf) {
#pragma unroll
    for (int c = 0; c < BM * 8 / 256; ++c) {
      int cc = c * 256 + tid;
      int r = cc >> 3, s = cc & 7;
      int ss = s ^ (r & 7);  // inverse-swizzled source slot
      async_ld16(Ap + (size_t)r * Kstride + k0 + ss * 8, &As[bf][cc * 8]);
    }
#pragma unroll
    for (int c = 0; c < BN * 8 / 256; ++c) {
      int cc = c * 256 + tid;
      int r = cc >> 3, s = cc & 7;
      int ss = s ^ (r & 7);
      async_ld16(Wp + (size_t)r * Kstride + k0 + ss * 8, &Bs[bf][cc * 8]);
    }
  };

  const int nk = K / BK;
  stage(0, 0);
  __syncthreads();
  int buf = 0;
  for (int t = 0; t < nk; ++t) {
    if (t + 1 < nk) stage((t + 1) * BK, buf ^ 1);
    bf16x8 af[WM][2], bfr[WN][2];
#pragma unroll
    for (int i = 0; i < WM; ++i) {
      int row = wm * WM * 16 + i * 16 + l15;
#pragma unroll
      for (int kf = 0; kf < 2; ++kf)
        af[i][kf] = *(const bf16x8*)&As[buf][row * 64 + (((kf * 4 + lg) ^ (row & 7)) * 8)];
    }
#pragma unroll
    for (int j = 0; j < WN; ++j) {
      int row = wn * WN * 16 + j * 16 + l15;
#pragma unroll
      for (int kf = 0; kf < 2; ++kf)
        bfr[j][kf] = *(const bf16x8*)&Bs[buf][row * 64 + (((kf * 4 + lg) ^ (row & 7)) * 8)];
    }
#pragma unroll
    for (int kf = 0; kf < 2; ++kf)
#pragma unroll
      for (int i = 0; i < WM; ++i)
#pragma unroll
        for (int j = 0; j < WN; ++j)
          acc[i][j] = __builtin_amdgcn_mfma_f32_16x16x32_bf16(af[i][kf], bfr[j][kf], acc[i][j], 0, 0, 0);
    __syncthreads();
    buf ^= 1;
  }

  if constexpr (EPI == 6) {
    const bool isV = ((tn & 1023) >= 512);
    const int lyr = tn >> 10;
    const int b = tm >> 11;
    const int sbase = tm & (Sc - 1);
    if (isV) {
      // V half: transpose 64(s) x 128(d) tile through LDS, coalesced stores.
      __bf16* T = (__bf16*)&As[0][0];  // [128 d][64 s], 16B-slot XOR swizzle
#pragma unroll
      for (int i = 0; i < WM; ++i) {
#pragma unroll
        for (int j = 0; j < WN; ++j) {
          const int d = wn * WN * 16 + j * 16 + l15;   // 0..127
          const int dg = (tn & 511) + d;               // 0..511 within layer V
          const float bv = bias2[lyr * 512 + dg];
          const int s0 = wm * WM * 16 + i * 16 + lg * 4;
          bf16x4 pk;
#pragma unroll
          for (int r = 0; r < 4; ++r) pk[r] = (__bf16)(acc[i][j][r] + bv);
          const int slot = (s0 >> 3) ^ (d & 7);
          *(bf16x4*)&T[d * 64 + slot * 8 + (s0 & 7)] = pk;
        }
      }
      __syncthreads();
      const int rr = tid >> 3;   // 0..31
      const int c8 = tid & 7;    // s-slot
#pragma unroll
      for (int pass = 0; pass < 4; ++pass) {
        const int d = pass * 32 + rr;
        const int slot = c8 ^ (d & 7);
        bf16x8 v8 = *(const bf16x8*)&T[d * 64 + slot * 8];
        const int dg = (tn & 511) + d;
        const int h = dg >> 6, dh = dg & 63;
        *(bf16x8*)&outb2[((((size_t)(lyr * Bc + b) * Hc + h)) * DHc + dh) * Sc +
                         sbase + c8 * 8] = v8;
      }
    } else {
      // K half: near-coalesced direct stores (789-baseline version)
#pragma unroll
      for (int i = 0; i < WM; ++i) {
#pragma unroll
        for (int j = 0; j < WN; ++j) {
          const int d = wn * WN * 16 + j * 16 + l15;
          const int dg = (tn & 511) + d;
          const float bv = bias[lyr * 512 + dg];
          const int h = dg >> 6, dh = dg & 63;
#pragma unroll
          for (int r = 0; r < 4; ++r) {
            const int s = sbase + wm * WM * 16 + i * 16 + lg * 4 + r;
            outb[((((size_t)(lyr * Bc + b) * Hc + h)) * Sc + s) * DHc + dh] =
                (__bf16)(acc[i][j][r] + bv);
          }
        }
      }
    }
    return;
  }

#pragma unroll
  for (int i = 0; i < WM; ++i) {
#pragma unroll
    for (int j = 0; j < WN; ++j) {
      const int n = tn + wn * WN * 16 + j * 16 + l15;
      float bv;
      if constexpr (EPI == 0) {
        bv = (z == 0) ? bias[n] : 0.f;
      } else {
        bv = bias[n];
      }
#pragma unroll
      for (int r = 0; r < 4; ++r) {
        const int m = tm + wm * WM * 16 + i * 16 + lg * 4 + r;
        float v = acc[i][j][r] + bv;
        if constexpr (EPI == 0) {
          outf[(size_t)z * M * N + (size_t)m * N + n] = v;
        } else if constexpr (EPI == 1) {
          int b = m >> 11, s = m & (Sc - 1);
          int h = n >> 6, dh = n & 63;
          outb[(((size_t)(b * Hc + h)) * Sc + s) * DHc + dh] = (__bf16)(v * scale);
        } else if constexpr (EPI == 4) {
          float lv = v > 0.f ? v : 0.01f * v;
          outb[(size_t)m * N + n] = (__bf16)lv;
        }
      }
    }
  }
}

// ---------------- flash attention with K-split, swapped QK^T ----------------
// VARIANT 0: mask bias loaded in-loop for the current tile (789 baseline).
// VARIANT 1: mask bias register-prefetched one tile ahead.
// A/B instrumentation: layers 0/2/4 run V0, layers 1/3/5 run V1.
template <int VARIANT>
__global__ __launch_bounds__(256, 5) void attn_kernel(
    const __bf16* __restrict__ q, const __bf16* __restrict__ k,
    const __bf16* __restrict__ vt, const float* __restrict__ kb,
    __bf16* __restrict__ Opart, float* __restrict__ mpart,
    float* __restrict__ lpart) {
  const int bid = blockIdx.x;
  const int o = (bid & 7) * 128 + (bid >> 3);  // bijective (1024 = 8*128)
  const int qb = o & 31;
  const int p = o >> 5;      // 0..31 = bh*NS + z
  const int bh = p >> 1;
  const int z = p & 1;
  const int b = bh >> 3;
  const int w = threadIdx.x >> 6;
  const int l = threadIdx.x & 63;
  const int l15 = l & 15;
  const int lg = l >> 4;
  const int tid = threadIdx.x;
  const int qbase = qb * 64 + w * 16;
  const int k0 = z * KCHUNK;

  const __bf16* qp = q + ((size_t)bh * Sc + qbase) * DHc;
  const __bf16* kp = k + (size_t)bh * Sc * DHc;
  const __bf16* vp = vt + (size_t)bh * DHc * Sc;
  const float* kbp = kb + (size_t)b * Sc;

  bf16x8 qf[2];
  qf[0] = *(const bf16x8*)(qp + l15 * DHc + lg * 8);
  qf[1] = *(const bf16x8*)(qp + l15 * DHc + 32 + lg * 8);

  bf16x8 onesf;
#pragma unroll
  for (int i = 0; i < 8; ++i) onesf[i] = (__bf16)1.0f;

  f32x4 oacc[4] = {};
  f32x4 lacc = {};
  float mr = -1e30f;  // running max for q = l15 (converged across lane groups)

  __shared__ __bf16 Ks[2][4096];
  __shared__ __bf16 Vs[2][4096];

  auto stage = [&](int t, int bf) {
    const int kt = k0 + t * 64;
#pragma unroll
    for (int ii = 0; ii < 2; ++ii) {
      int i = ii * 256 + tid;          // 16B slot id, 0..511
      int r = i >> 3;                  // row 0..63
      int bsrc = (i & 7) ^ (r & 7);    // inverse-swizzled source slot
      async_ld16(kp + (size_t)(kt + r) * DHc + bsrc * 8, &Ks[bf][i * 8]);
      async_ld16(vp + (size_t)r * Sc + kt + bsrc * 8, &Vs[bf][i * 8]);
    }
  };

  stage(0, 0);
  float4 mb4[4];
  if constexpr (VARIANT == 1) {
#pragma unroll
    for (int cb = 0; cb < 4; ++cb)
      mb4[cb] = *(const float4*)&kbp[k0 + cb * 16 + lg * 4];
  }
  __syncthreads();

  constexpr int NT = KCHUNK / 64;
  int buf = 0;
  for (int t = 0; t < NT; ++t) {
    const int kt = k0 + t * 64;
    if (t + 1 < NT) stage(t + 1, buf ^ 1);

    float4 mbn4[4];
    if constexpr (VARIANT == 1) {
      if (t + 1 < NT) {
#pragma unroll
        for (int cb = 0; cb < 4; ++cb)
          mbn4[cb] = *(const float4*)&kbp[kt + 64 + cb * 16 + lg * 4];
      }
    } else {
#pragma unroll
      for (int cb = 0; cb < 4; ++cb)
        mb4[cb] = *(const float4*)&kbp[kt + cb * 16 + lg * 4];
    }

    // ---- swapped QK^T: S[k][q], lane holds k=cb*16+lg*4+r, q=l15 ----
    f32x4 sacc[4] = {};
    __builtin_amdgcn_s_setprio(1);
#pragma unroll
    for (int kf = 0; kf < 2; ++kf) {
#pragma unroll
      for (int cb = 0; cb < 4; ++cb) {
        int row = cb * 16 + l15;
        bf16x8 kfr = *(const bf16x8*)&Ks[buf][row * 64 + (((kf * 4 + lg) ^ (row & 7)) * 8)];
        sacc[cb] = __builtin_amdgcn_mfma_f32_16x16x32_bf16(kfr, qf[kf], sacc[cb], 0, 0, 0);
      }
    }
    __builtin_amdgcn_s_setprio(0);
    sacc[0][0] += mb4[0].x; sacc[0][1] += mb4[0].y; sacc[0][2] += mb4[0].z; sacc[0][3] += mb4[0].w;
    sacc[1][0] += mb4[1].x; sacc[1][1] += mb4[1].y; sacc[1][2] += mb4[1].z; sacc[1][3] += mb4[1].w;
    sacc[2][0] += mb4[2].x; sacc[2][1] += mb4[2].y; sacc[2][2] += mb4[2].z; sacc[2][3] += mb4[2].w;
    sacc[3][0] += mb4[3].x; sacc[3][1] += mb4[3].y; sacc[3][2] += mb4[3].z; sacc[3][3] += mb4[3].w;

    // ---- row max: 15 local fmax + 2 shfl_xor (lanes with same l15) ----
    float mx = sacc[0][0];
#pragma unroll
    for (int cb = 0; cb < 4; ++cb)
#pragma unroll
      for (int r = 0; r < 4; ++r) mx = fmaxf(mx, sacc[cb][r]);
    mx = fmaxf(mx, __shfl_xor(mx, 16, 64));
    mx = fmaxf(mx, __shfl_xor(mx, 32, 64));

    if (__any(mx > mr + 8.f)) {   // defer-max: rare rescale
      float mn = fmaxf(mr, mx);
      float f = __expf(mr - mn);
      mr = mn;
      // redistribute f (held at lane l15=q) to output layout q = lg*4+j
      float fj[4];
#pragma unroll
      for (int j = 0; j < 4; ++j) fj[j] = __shfl(f, lg * 4 + j, 64);
#pragma unroll
      for (int j = 0; j < 4; ++j) lacc[j] *= fj[j];
#pragma unroll
      for (int db = 0; db < 4; ++db)
#pragma unroll
        for (int j = 0; j < 4; ++j) oacc[db][j] *= fj[j];
    }

    // ---- P = exp(S - m), pack to bf16 words pw[cb][w2] ----
    unsigned pw[4][2];
#pragma unroll
    for (int cb = 0; cb < 4; ++cb) {
#pragma unroll
      for (int w2 = 0; w2 < 2; ++w2) {
        union { __bf16 h[2]; unsigned u; } cu;
        cu.h[0] = (__bf16)__expf(sacc[cb][2 * w2] - mr);
        cu.h[1] = (__bf16)__expf(sacc[cb][2 * w2 + 1] - mr);
        pw[cb][w2] = cu.u;
      }
    }

    // ---- in-register exchange: build PV A-fragment P[q=l15][k=kf*32+lg*8+e]
    const int srcA = ((lg & 1) * 2) * 16 + l15;
    const int srcB = srcA + 16;
    const bool hi = (lg >> 1) & 1;
#pragma unroll
    for (int kf = 0; kf < 2; ++kf) {
      unsigned t0a = __shfl((int)pw[kf * 2][0], srcA, 64);
      unsigned t0b = __shfl((int)pw[kf * 2 + 1][0], srcA, 64);
      unsigned t1a = __shfl((int)pw[kf * 2][1], srcA, 64);
      unsigned t1b = __shfl((int)pw[kf * 2 + 1][1], srcA, 64);
      unsigned t2a = __shfl((int)pw[kf * 2][0], srcB, 64);
      unsigned t2b = __shfl((int)pw[kf * 2 + 1][0], srcB, 64);
      unsigned t3a = __shfl((int)pw[kf * 2][1], srcB, 64);
      unsigned t3b = __shfl((int)pw[kf * 2 + 1][1], srcB, 64);
      union { unsigned u[4]; bf16x8 v; } pa;
      pa.u[0] = hi ? t0b : t0a;
      pa.u[1] = hi ? t1b : t1a;
      pa.u[2] = hi ? t2b : t2a;
      pa.u[3] = hi ? t3b : t3a;
      __builtin_amdgcn_s_setprio(1);
      lacc = __builtin_amdgcn_mfma_f32_16x16x32_bf16(pa.v, onesf, lacc, 0, 0, 0);
#pragma unroll
      for (int db = 0; db < 4; ++db) {
        int row = db * 16 + l15;
        bf16x8 vf = *(const bf16x8*)&Vs[buf][row * 64 + (((kf * 4 + lg) ^ (row & 7)) * 8)];
        oacc[db] = __builtin_amdgcn_mfma_f32_16x16x32_bf16(pa.v, vf, oacc[db], 0, 0, 0);
      }
      __builtin_amdgcn_s_setprio(0);
    }
    if constexpr (VARIANT == 1) {
      if (t + 1 < NT) {
#pragma unroll
        for (int cb = 0; cb < 4; ++cb) mb4[cb] = mbn4[cb];
      }
    }
    __syncthreads();   // drains stage(t+1) vmem writes + protects buf reuse
    buf ^= 1;
  }

  // ---- write unnormalized partial ----
  const size_t obase = (((size_t)(z * Bc * Hc + bh)) * Sc + qbase) * DHc;
#pragma unroll
  for (int db = 0; db < 4; ++db)
#pragma unroll
    for (int j = 0; j < 4; ++j)
      Opart[obase + (size_t)(lg * 4 + j) * DHc + db * 16 + l15] = (__bf16)oacc[db][j];
  const int row0 = (z * Bc * Hc + bh) * Sc + qbase;
  if (lg == 0) mpart[row0 + l15] = mr;      // m held at lane l15 = q
  if (l15 == 0) {
#pragma unroll
    for (int j = 0; j < 4; ++j) lpart[row0 + lg * 4 + j] = lacc[j];
  }
}

// ---------------- combine split partials -> bf16 [B,S,D] (vectorized) -------
__global__ __launch_bounds__(256) void attn_combine(
    const __bf16* __restrict__ Opart, const float* __restrict__ mpart,
    const float* __restrict__ lpart, __bf16* __restrict__ out) {
  int t = blockIdx.x * 256 + threadIdx.x;  // over BH*S*8 (8 elems per thread)
  int g = t & 7;
  int row = t >> 3;          // bh*Sc + s
  int bh = row >> 11, s = row & (Sc - 1);
  constexpr int RSTRIDE = Bc * Hc * Sc;  // rows per split
  float m0 = mpart[row], m1 = mpart[RSTRIDE + row];
  float l0 = lpart[row], l1 = lpart[RSTRIDE + row];
  float M = fmaxf(m0, m1);
  float e0 = __expf(m0 - M), e1 = __expf(m1 - M);
  float inv = 1.0f / (e0 * l0 + e1 * l1);
  bf16x8 o0 = *(const bf16x8*)&Opart[(size_t)row * DHc + g * 8];
  bf16x8 o1 = *(const bf16x8*)&Opart[((size_t)RSTRIDE + row) * DHc + g * 8];
  bf16x8 r;
#pragma unroll
  for (int e = 0; e < 8; ++e)
    r[e] = (__bf16)((e0 * (float)o0[e] + e1 * (float)o1[e]) * inv);
  int b = bh >> 3, h = bh & 7;
  *(bf16x8*)&out[(((size_t)b * Sc + s)) * Dc + h * DHc + g * 8] = r;
}

// ---------------- residual add + LayerNorm (vectorized, 2 rows/block) -------
// x_out = LN((res + res2) * mask + xin) * g + b ; writes fp32 and bf16.
__global__ __launch_bounds__(256) void add_ln_kernel(
    const float* __restrict__ res, const float* __restrict__ res2,
    const int* __restrict__ rmask, const float* __restrict__ xin,
    const float* __restrict__ g, const float* __restrict__ bb,
    float* __restrict__ xo, __bf16* __restrict__ xbo) {
  const int tid = threadIdx.x;
  const int rl = tid >> 7;                 // row within pair (0/1)
  const int row = blockIdx.x * 2 + rl;
  const int ci = (tid & 127) * 4;          // column start
  const size_t base = (size_t)row * Dc + ci;
  const float4 a = *(const float4*)(res + base);
  const float4 a2 = *(const float4*)(res2 + base);
  const float4 xv = *(const float4*)(xin + base);
  const float mfac = (float)rmask[row];
  float4 v;
  v.x = (a.x + a2.x) * mfac + xv.x;
  v.y = (a.y + a2.y) * mfac + xv.y;
  v.z = (a.z + a2.z) * mfac + xv.z;
  v.w = (a.w + a2.w) * mfac + xv.w;
  float s = v.x + v.y + v.z + v.w;
#pragma unroll
  for (int d = 1; d < 64; d <<= 1) s += __shfl_xor(s, d, 64);
  __shared__ float red[4], red2[4];
  if ((tid & 63) == 0) red[tid >> 6] = s;
  __syncthreads();
  float mean = (red[rl * 2] + red[rl * 2 + 1]) * (1.0f / Dc);
  float4 dv;
  dv.x = v.x - mean; dv.y = v.y - mean; dv.z = v.z - mean; dv.w = v.w - mean;
  float qq = dv.x * dv.x + dv.y * dv.y + dv.z * dv.z + dv.w * dv.w;
#pragma unroll
  for (int d = 1; d < 64; d <<= 1) qq += __shfl_xor(qq, d, 64);
  if ((tid & 63) == 0) red2[tid >> 6] = qq;
  __syncthreads();
  float var = (red2[rl * 2] + red2[rl * 2 + 1]) * (1.0f / Dc);
  float rs = rsqrtf(var + 1e-5f);
  const float4 gv = *(const float4*)(g + ci);
  const float4 bv = *(const float4*)(bb + ci);
  float4 ov;
  ov.x = dv.x * rs * gv.x + bv.x;
  ov.y = dv.y * rs * gv.y + bv.y;
  ov.z = dv.z * rs * gv.z + bv.z;
  ov.w = dv.w * rs * gv.w + bv.w;
  *(float4*)(xo + base) = ov;
  bf16x4 ob;
  ob[0] = (__bf16)ov.x; ob[1] = (__bf16)ov.y; ob[2] = (__bf16)ov.z; ob[3] = (__bf16)ov.w;
  *(bf16x4*)(xbo + base) = ob;
}

extern "C" void kernel_launch(void* const* d_in, const int* in_sizes, int n_in,
                              void* d_out, int out_size, void* d_ws, size_t ws_size,
                              hipStream_t stream) {
  (void)in_sizes; (void)n_in; (void)out_size; (void)ws_size;
  const float* query = (const float*)d_in[0];
  const float* key   = (const float*)d_in[1];
  const int* qmask   = (const int*)d_in[2];
  const int* kmask   = (const int*)d_in[3];
  const float* Wq = (const float*)d_in[4];
  const float* bq = (const float*)d_in[5];
  const float* Wk = (const float*)d_in[6];
  const float* bk = (const float*)d_in[7];
  const float* Wv = (const float*)d_in[8];
  const float* bv = (const float*)d_in[9];
  const float* Wo = (const float*)d_in[10];
  const float* bo = (const float*)d_in[11];
  const float* ln1g = (const float*)d_in[12];
  const float* ln1b = (const float*)d_in[13];
  const float* fw1 = (const float*)d_in[14];
  const float* fb1 = (const float*)d_in[15];
  const float* fw2 = (const float*)d_in[16];
  const float* fb2 = (const float*)d_in[17];
  const float* ln2g = (const float*)d_in[18];
  const float* ln2b = (const float*)d_in[19];

  char* ws = (char*)d_ws;
  size_t off = 0;
  auto carve = [&](size_t bytes) -> void* {
    void* p = ws + off;
    off += (bytes + 255) & ~(size_t)255;
    return p;
  };
  float* x_f    = (float*)carve((size_t)Mc * Dc * 4);
  float* tmp_f  = (float*)carve((size_t)2 * Mc * Dc * 4);  // split-K partials z=0,1
  __bf16* x_b   = (__bf16*)carve((size_t)Mc * Dc * 2);
  __bf16* key_b = (__bf16*)carve((size_t)Mc * Dc * 2);
  __bf16* q_b   = (__bf16*)carve((size_t)Mc * Dc * 2);
  __bf16* at_b  = (__bf16*)carve((size_t)Mc * Dc * 2);
  __bf16* h_b   = (__bf16*)carve((size_t)Mc * FFc * 2);
  __bf16* k_all = (__bf16*)carve((size_t)LAYERS * Mc * Dc * 2);
  __bf16* vt_all= (__bf16*)carve((size_t)LAYERS * Mc * Dc * 2);
  __bf16* wq_b  = (__bf16*)carve((size_t)LAYERS * Dc * Dc * 2);
  __bf16* wkv_b = (__bf16*)carve((size_t)LAYERS * 2 * Dc * Dc * 2);
  __bf16* wo_b  = (__bf16*)carve((size_t)LAYERS * Dc * Dc * 2);
  __bf16* w1_b  = (__bf16*)carve((size_t)LAYERS * FFc * Dc * 2);
  __bf16* w2_b  = (__bf16*)carve((size_t)LAYERS * Dc * FFc * 2);
  float* ml_f   = (float*)carve((size_t)NS * Bc * Hc * Sc * 4 * 2);  // m,l partials
  float* kb_f   = (float*)carve((size_t)Bc * Sc * 4);                // key bias

  __bf16* opart_b = h_b;  // reuse (free during attention)
  float* mpart_f = ml_f;
  float* lpart_f = ml_f + (size_t)NS * Bc * Hc * Sc;
  float* tmp2_f = tmp_f + (size_t)Mc * Dc;

  // fused conversions: 19922944 elements / 4 per thread / 256 per block
  cvt_all<<<19456, 256, 0, stream>>>(Wq, Wo, fw1, fw2, query, key,
                                     wq_b, wo_b, w1_b, w2_b, x_b, key_b, x_f);
  cvt_kv_kernel<<<LAYERS * 2 * Dc * Dc / 1024, 256, 0, stream>>>(Wk, Wv, wkv_b);
  kbias_kernel<<<Bc * Sc / 256, 256, 0, stream>>>(kmask, kb_f, Bc * Sc);

  const dim3 blk(256);
  const dim3 gP64(Dc / 64, Mc / 64);                // 512 blocks (Q proj)
  const dim3 gOP(Dc / 64, Mc / 64, 2);              // O-proj split-K, 1024 blocks
  const dim3 gFF2(Dc / 64, Mc / 64, 2);             // FFN2 split-K, 1024 blocks
  const dim3 gKV(LAYERS * 2 * Dc / 128, Mc / 64);   // 48 x 64 = 3072 blocks
  const dim3 gFF1(FFc / 128, Mc / 64);              // 64x128 tiles, 1024 blocks
  const dim3 gAttn(Sc / 64 * Bc * Hc * NS);         // 1024, 1-D + XCD swizzle
  const dim3 gComb(Bc * Hc * Sc * 8 / 256);         // 1024, 8 elems/thread
  const dim3 gLN(Mc / 2);                           // 2 rows per block

  // all layers' K/V projections in one batched GEMM (depends only on `key`)
  gemm_bt<64, 128, 2, 4, 6><<<gKV, blk, 0, stream>>>(
      key_b, wkv_b, bk, bv, nullptr, k_all, vt_all, 1.0f,
      Mc, LAYERS * 2 * Dc, Dc, Dc);

  for (int i = 0; i < LAYERS; ++i) {
    const __bf16* wq_i = wq_b + (size_t)i * Dc * Dc;
    const __bf16* wo_i = wo_b + (size_t)i * Dc * Dc;
    const __bf16* w1_i = w1_b + (size_t)i * FFc * Dc;
    const __bf16* w2_i = w2_b + (size_t)i * Dc * FFc;
    const __bf16* k_i  = k_all + (size_t)i * Mc * Dc;
    const __bf16* vt_i = vt_all + (size_t)i * Mc * Dc;

    gemm_bt<64, 64, 2, 2, 1><<<gP64, blk, 0, stream>>>(
        x_b, wq_i, bq + i * Dc, nullptr, nullptr, q_b, nullptr, 0.125f,
        Mc, Dc, Dc, Dc);
    if (i & 1)
      attn_kernel<1><<<gAttn, blk, 0, stream>>>(q_b, k_i, vt_i, kb_f,
                                                opart_b, mpart_f, lpart_f);
    else
      attn_kernel<0><<<gAttn, blk, 0, stream>>>(q_b, k_i, vt_i, kb_f,
                                                opart_b, mpart_f, lpart_f);
    attn_combine<<<gComb, blk, 0, stream>>>(opart_b, mpart_f, lpart_f, at_b);
    gemm_bt<64, 64, 2, 2, 0><<<gOP, blk, 0, stream>>>(
        at_b, wo_i, bo + i * Dc, nullptr, tmp_f, nullptr, nullptr, 1.0f,
        Mc, Dc, Dc / 2, Dc);
    add_ln_kernel<<<gLN, blk, 0, stream>>>(tmp_f, tmp2_f, qmask, x_f,
                                           ln1g + i * Dc, ln1b + i * Dc, x_f, x_b);
    gemm_bt<64, 128, 2, 4, 4><<<gFF1, blk, 0, stream>>>(
        x_b, w1_i, fb1 + i * FFc, nullptr, nullptr, h_b, nullptr, 1.0f,
        Mc, FFc, Dc, Dc);
    gemm_bt<64, 64, 2, 2, 0><<<gFF2, blk, 0, stream>>>(
        h_b, w2_i, fb2 + i * Dc, nullptr, tmp_f, nullptr, nullptr, 1.0f,
        Mc, Dc, FFc / 2, FFc);
    add_ln_kernel<<<gLN, blk, 0, stream>>>(tmp_f, tmp2_f, qmask, x_f,
                                           ln2g + i * Dc, ln2b + i * Dc, x_f, x_b);
  }
  hipMemcpyAsync(d_out, x_f, (size_t)Mc * Dc * 4, hipMemcpyDeviceToDevice, stream);
}

// Round 15
// 762.707 us; speedup vs baseline: 1.2021x; 1.0956x over previous
//
#include <hip/hip_runtime.h>
#include <stdint.h>

constexpr int LAYERS = 6;
constexpr int Bc = 2, Sc = 2048, Dc = 512, Hc = 8, DHc = 64, FFc = 2048;
constexpr int Mc = Bc * Sc;  // 4096
constexpr int NS = 2;        // attention K-splits
constexpr int KCHUNK = Sc / NS;  // 1024

typedef __attribute__((ext_vector_type(8))) __bf16 bf16x8;
typedef __attribute__((ext_vector_type(4))) __bf16 bf16x4;
typedef __attribute__((ext_vector_type(4))) float f32x4;

__device__ __forceinline__ void async_ld16(const void* g, void* lds) {
  __builtin_amdgcn_global_load_lds(
      (const __attribute__((address_space(1))) uint32_t*)g,
      (__attribute__((address_space(3))) uint32_t*)lds, 16, 0, 0);
}

// ---------------- fused fp32 -> bf16 conversion of all inputs ----------------
// Segments: Wq | Wo | fw1 | fw2 | query(+f32 copy) | key
__global__ __launch_bounds__(256) void cvt_all(
    const float* __restrict__ Wq, const float* __restrict__ Wo,
    const float* __restrict__ fw1, const float* __restrict__ fw2,
    const float* __restrict__ query, const float* __restrict__ key,
    __bf16* __restrict__ wq_b, __bf16* __restrict__ wo_b,
    __bf16* __restrict__ w1_b, __bf16* __restrict__ w2_b,
    __bf16* __restrict__ x_b, __bf16* __restrict__ key_b,
    float* __restrict__ x_f) {
  size_t i = ((size_t)blockIdx.x * 256 + threadIdx.x) * 4;
  constexpr size_t nW = (size_t)LAYERS * Dc * Dc;   // 1572864
  constexpr size_t nF = (size_t)LAYERS * FFc * Dc;  // 6291456
  constexpr size_t nX = (size_t)Mc * Dc;            // 2097152
  const float* src;
  __bf16* dst;
  float* fdst = nullptr;
  if (i < nW) { src = Wq + i; dst = wq_b + i; }
  else if (i < 2 * nW) { size_t j = i - nW; src = Wo + j; dst = wo_b + j; }
  else if (i < 2 * nW + nF) { size_t j = i - 2 * nW; src = fw1 + j; dst = w1_b + j; }
  else if (i < 2 * nW + 2 * nF) { size_t j = i - 2 * nW - nF; src = fw2 + j; dst = w2_b + j; }
  else if (i < 2 * nW + 2 * nF + nX) {
    size_t j = i - 2 * nW - 2 * nF;
    src = query + j; dst = x_b + j; fdst = x_f + j;
  } else {
    size_t j = i - 2 * nW - 2 * nF - nX;
    src = key + j; dst = key_b + j;
  }
  const float4 v = *(const float4*)src;
  bf16x4 o;
  o[0] = (__bf16)v.x; o[1] = (__bf16)v.y; o[2] = (__bf16)v.z; o[3] = (__bf16)v.w;
  *(bf16x4*)dst = o;
  if (fdst) *(float4*)fdst = v;
}

// interleave all layers' Wk,Wv into one bf16 buffer [L][2][D][D]
__global__ __launch_bounds__(256) void cvt_kv_kernel(const float* __restrict__ Wk,
                                                     const float* __restrict__ Wv,
                                                     __bf16* __restrict__ out) {
  size_t i = ((size_t)blockIdx.x * 256 + threadIdx.x) * 4;
  int n = (int)(i / ((size_t)Dc * Dc));  // lyr*2 + p
  int lyr = n >> 1, p = n & 1;
  size_t idx = i - (size_t)n * Dc * Dc;
  const float* src = (p ? Wv : Wk) + (size_t)lyr * Dc * Dc + idx;
  const float4 v = *(const float4*)src;
  bf16x4 o;
  o[0] = (__bf16)v.x; o[1] = (__bf16)v.y; o[2] = (__bf16)v.z; o[3] = (__bf16)v.w;
  *(bf16x4*)(out + i) = o;
}

// key mask -> additive bias
__global__ __launch_bounds__(256) void kbias_kernel(const int* __restrict__ km,
                                                    float* __restrict__ kb, int n) {
  int i = blockIdx.x * 256 + threadIdx.x;
  if (i < n) kb[i] = km[i] ? 0.f : -1e30f;
}

// ---------------- GEMM: C[M,N] = A[M,K] @ W[N,K]^T + bias, fused epilogues ----
// BK=64, 2-phase double-buffered LDS, both-sides XOR swizzle (slot ^ (row&7)).
// Split-K via blockIdx.z: K = per-block chunk, Kstride = full row stride.
// EPI: 0 = f32 row-major partial (outf + z*M*N), bias at z==0
//      1 = bf16 split-head [B,H,S,DH], value *= scale    (Q projection)
//      4 = bf16 row-major, leaky-relu(0.01)              (FFN1)
//      6 = batched KV: N = L*1024; K -> outb [L,B,H,S,DH];
//          V -> outb2 [L,B,H,DH,S] via LDS-transposed coalesced stores
template <int BM, int BN, int WM, int WN, int EPI>
__global__ __launch_bounds__(256) void gemm_bt(
    const __bf16* __restrict__ A, const __bf16* __restrict__ W,
    const float* __restrict__ bias, const float* __restrict__ bias2,
    float* __restrict__ outf, __bf16* __restrict__ outb,
    __bf16* __restrict__ outb2, float scale,
    int M, int N, int K, int Kstride) {
  constexpr int BK = 64;
  __shared__ __bf16 As[2][BM * BK];
  __shared__ __bf16 Bs[2][BN * BK];
  const int tid = threadIdx.x;
  const int l15 = tid & 15;
  const int lg = (tid & 63) >> 4;
  const int w = tid >> 6;
  const int wm = w >> 1, wn = w & 1;
  const int tm = blockIdx.y * BM;
  const int tn = blockIdx.x * BN;
  const int z = blockIdx.z;
  const __bf16* Ap = A + (size_t)tm * Kstride + (size_t)z * K;
  const __bf16* Wp = W + (size_t)tn * Kstride + (size_t)z * K;
  f32x4 acc[WM][WN] = {};

  auto stage = [&](int k0, int bf) {
#pragma unroll
    for (int c = 0; c < BM * 8 / 256; ++c) {
      int cc = c * 256 + tid;
      int r = cc >> 3, s = cc & 7;
      int ss = s ^ (r & 7);  // inverse-swizzled source slot
      async_ld16(Ap + (size_t)r * Kstride + k0 + ss * 8, &As[bf][cc * 8]);
    }
#pragma unroll
    for (int c = 0; c < BN * 8 / 256; ++c) {
      int cc = c * 256 + tid;
      int r = cc >> 3, s = cc & 7;
      int ss = s ^ (r & 7);
      async_ld16(Wp + (size_t)r * Kstride + k0 + ss * 8, &Bs[bf][cc * 8]);
    }
  };

  const int nk = K / BK;
  stage(0, 0);
  __syncthreads();
  int buf = 0;
  for (int t = 0; t < nk; ++t) {
    if (t + 1 < nk) stage((t + 1) * BK, buf ^ 1);
    bf16x8 af[WM][2], bfr[WN][2];
#pragma unroll
    for (int i = 0; i < WM; ++i) {
      int row = wm * WM * 16 + i * 16 + l15;
#pragma unroll
      for (int kf = 0; kf < 2; ++kf)
        af[i][kf] = *(const bf16x8*)&As[buf][row * 64 + (((kf * 4 + lg) ^ (row & 7)) * 8)];
    }
#pragma unroll
    for (int j = 0; j < WN; ++j) {
      int row = wn * WN * 16 + j * 16 + l15;
#pragma unroll
      for (int kf = 0; kf < 2; ++kf)
        bfr[j][kf] = *(const bf16x8*)&Bs[buf][row * 64 + (((kf * 4 + lg) ^ (row & 7)) * 8)];
    }
#pragma unroll
    for (int kf = 0; kf < 2; ++kf)
#pragma unroll
      for (int i = 0; i < WM; ++i)
#pragma unroll
        for (int j = 0; j < WN; ++j)
          acc[i][j] = __builtin_amdgcn_mfma_f32_16x16x32_bf16(af[i][kf], bfr[j][kf], acc[i][j], 0, 0, 0);
    __syncthreads();
    buf ^= 1;
  }

  if constexpr (EPI == 6) {
    const bool isV = ((tn & 1023) >= 512);
    const int lyr = tn >> 10;
    const int b = tm >> 11;
    const int sbase = tm & (Sc - 1);
    if (isV) {
      // V half: transpose 64(s) x 128(d) tile through LDS, coalesced stores.
      __bf16* T = (__bf16*)&As[0][0];  // [128 d][64 s], 16B-slot XOR swizzle
#pragma unroll
      for (int i = 0; i < WM; ++i) {
#pragma unroll
        for (int j = 0; j < WN; ++j) {
          const int d = wn * WN * 16 + j * 16 + l15;   // 0..127
          const int dg = (tn & 511) + d;               // 0..511 within layer V
          const float bv = bias2[lyr * 512 + dg];
          const int s0 = wm * WM * 16 + i * 16 + lg * 4;
          bf16x4 pk;
#pragma unroll
          for (int r = 0; r < 4; ++r) pk[r] = (__bf16)(acc[i][j][r] + bv);
          const int slot = (s0 >> 3) ^ (d & 7);
          *(bf16x4*)&T[d * 64 + slot * 8 + (s0 & 7)] = pk;
        }
      }
      __syncthreads();
      const int rr = tid >> 3;   // 0..31
      const int c8 = tid & 7;    // s-slot
#pragma unroll
      for (int pass = 0; pass < 4; ++pass) {
        const int d = pass * 32 + rr;
        const int slot = c8 ^ (d & 7);
        bf16x8 v8 = *(const bf16x8*)&T[d * 64 + slot * 8];
        const int dg = (tn & 511) + d;
        const int h = dg >> 6, dh = dg & 63;
        *(bf16x8*)&outb2[((((size_t)(lyr * Bc + b) * Hc + h)) * DHc + dh) * Sc +
                         sbase + c8 * 8] = v8;
      }
    } else {
      // K half: near-coalesced direct stores (789-baseline version)
#pragma unroll
      for (int i = 0; i < WM; ++i) {
#pragma unroll
        for (int j = 0; j < WN; ++j) {
          const int d = wn * WN * 16 + j * 16 + l15;
          const int dg = (tn & 511) + d;
          const float bv = bias[lyr * 512 + dg];
          const int h = dg >> 6, dh = dg & 63;
#pragma unroll
          for (int r = 0; r < 4; ++r) {
            const int s = sbase + wm * WM * 16 + i * 16 + lg * 4 + r;
            outb[((((size_t)(lyr * Bc + b) * Hc + h)) * Sc + s) * DHc + dh] =
                (__bf16)(acc[i][j][r] + bv);
          }
        }
      }
    }
    return;
  }

#pragma unroll
  for (int i = 0; i < WM; ++i) {
#pragma unroll
    for (int j = 0; j < WN; ++j) {
      const int n = tn + wn * WN * 16 + j * 16 + l15;
      float bv;
      if constexpr (EPI == 0) {
        bv = (z == 0) ? bias[n] : 0.f;
      } else {
        bv = bias[n];
      }
#pragma unroll
      for (int r = 0; r < 4; ++r) {
        const int m = tm + wm * WM * 16 + i * 16 + lg * 4 + r;
        float v = acc[i][j][r] + bv;
        if constexpr (EPI == 0) {
          outf[(size_t)z * M * N + (size_t)m * N + n] = v;
        } else if constexpr (EPI == 1) {
          int b = m >> 11, s = m & (Sc - 1);
          int h = n >> 6, dh = n & 63;
          outb[(((size_t)(b * Hc + h)) * Sc + s) * DHc + dh] = (__bf16)(v * scale);
        } else if constexpr (EPI == 4) {
          float lv = v > 0.f ? v : 0.01f * v;
          outb[(size_t)m * N + n] = (__bf16)lv;
        }
      }
    }
  }
}

// ---------------- flash attention with K-split, swapped QK^T ----------------
// 8-wave blocks (512 threads) covering 128 q rows: all 8 waves share one K/V
// LDS staging per tile (halves per-thread stage work and total K/V global
// reads). Per-wave logic identical to the proven 4-wave kernel. Mask bias is
// loaded IN-LOOP (V0 — the prefetch variant measured +22 us/dispatch in the
// R14 A/B and is banned). XCD-chunked swizzle keeps K/V L2-resident.
__global__ __launch_bounds__(512, 2) void attn_kernel(
    const __bf16* __restrict__ q, const __bf16* __restrict__ k,
    const __bf16* __restrict__ vt, const float* __restrict__ kb,
    __bf16* __restrict__ Opart, float* __restrict__ mpart,
    float* __restrict__ lpart) {
  const int bid = blockIdx.x;
  const int o = (bid & 7) * 64 + (bid >> 3);  // bijective (512 = 8*64)
  const int qb = o & 15;     // 16 q-tiles of 128 rows
  const int p = o >> 4;      // 0..31 = bh*NS + z
  const int bh = p >> 1;
  const int z = p & 1;
  const int b = bh >> 3;
  const int w = threadIdx.x >> 6;   // 0..7
  const int l = threadIdx.x & 63;
  const int l15 = l & 15;
  const int lg = l >> 4;
  const int tid = threadIdx.x;
  const int qbase = qb * 128 + w * 16;
  const int k0 = z * KCHUNK;

  const __bf16* qp = q + ((size_t)bh * Sc + qbase) * DHc;
  const __bf16* kp = k + (size_t)bh * Sc * DHc;
  const __bf16* vp = vt + (size_t)bh * DHc * Sc;
  const float* kbp = kb + (size_t)b * Sc;

  bf16x8 qf[2];
  qf[0] = *(const bf16x8*)(qp + l15 * DHc + lg * 8);
  qf[1] = *(const bf16x8*)(qp + l15 * DHc + 32 + lg * 8);

  bf16x8 onesf;
#pragma unroll
  for (int i = 0; i < 8; ++i) onesf[i] = (__bf16)1.0f;

  f32x4 oacc[4] = {};
  f32x4 lacc = {};
  float mr = -1e30f;  // running max for q = l15 (converged across lane groups)

  __shared__ __bf16 Ks[2][4096];
  __shared__ __bf16 Vs[2][4096];

  auto stage = [&](int t, int bf) {
    const int kt = k0 + t * 64;
    int i = tid;                     // 16B slot id, 0..511 (one per thread)
    int r = i >> 3;                  // row 0..63
    int bsrc = (i & 7) ^ (r & 7);    // inverse-swizzled source slot
    async_ld16(kp + (size_t)(kt + r) * DHc + bsrc * 8, &Ks[bf][i * 8]);
    async_ld16(vp + (size_t)r * Sc + kt + bsrc * 8, &Vs[bf][i * 8]);
  };

  stage(0, 0);
  __syncthreads();

  constexpr int NT = KCHUNK / 64;
  int buf = 0;
  for (int t = 0; t < NT; ++t) {
    const int kt = k0 + t * 64;
    if (t + 1 < NT) stage(t + 1, buf ^ 1);

    // mask bias for this tile (in-loop, V0): 4 aligned float4 loads
    float4 mb4[4];
#pragma unroll
    for (int cb = 0; cb < 4; ++cb)
      mb4[cb] = *(const float4*)&kbp[kt + cb * 16 + lg * 4];

    // ---- swapped QK^T: S[k][q], lane holds k=cb*16+lg*4+r, q=l15 ----
    f32x4 sacc[4] = {};
    __builtin_amdgcn_s_setprio(1);
#pragma unroll
    for (int kf = 0; kf < 2; ++kf) {
#pragma unroll
      for (int cb = 0; cb < 4; ++cb) {
        int row = cb * 16 + l15;
        bf16x8 kfr = *(const bf16x8*)&Ks[buf][row * 64 + (((kf * 4 + lg) ^ (row & 7)) * 8)];
        sacc[cb] = __builtin_amdgcn_mfma_f32_16x16x32_bf16(kfr, qf[kf], sacc[cb], 0, 0, 0);
      }
    }
    __builtin_amdgcn_s_setprio(0);
    sacc[0][0] += mb4[0].x; sacc[0][1] += mb4[0].y; sacc[0][2] += mb4[0].z; sacc[0][3] += mb4[0].w;
    sacc[1][0] += mb4[1].x; sacc[1][1] += mb4[1].y; sacc[1][2] += mb4[1].z; sacc[1][3] += mb4[1].w;
    sacc[2][0] += mb4[2].x; sacc[2][1] += mb4[2].y; sacc[2][2] += mb4[2].z; sacc[2][3] += mb4[2].w;
    sacc[3][0] += mb4[3].x; sacc[3][1] += mb4[3].y; sacc[3][2] += mb4[3].z; sacc[3][3] += mb4[3].w;

    // ---- row max: 15 local fmax + 2 shfl_xor (lanes with same l15) ----
    float mx = sacc[0][0];
#pragma unroll
    for (int cb = 0; cb < 4; ++cb)
#pragma unroll
      for (int r = 0; r < 4; ++r) mx = fmaxf(mx, sacc[cb][r]);
    mx = fmaxf(mx, __shfl_xor(mx, 16, 64));
    mx = fmaxf(mx, __shfl_xor(mx, 32, 64));

    if (__any(mx > mr + 8.f)) {   // defer-max: rare rescale
      float mn = fmaxf(mr, mx);
      float f = __expf(mr - mn);
      mr = mn;
      // redistribute f (held at lane l15=q) to output layout q = lg*4+j
      float fj[4];
#pragma unroll
      for (int j = 0; j < 4; ++j) fj[j] = __shfl(f, lg * 4 + j, 64);
#pragma unroll
      for (int j = 0; j < 4; ++j) lacc[j] *= fj[j];
#pragma unroll
      for (int db = 0; db < 4; ++db)
#pragma unroll
        for (int j = 0; j < 4; ++j) oacc[db][j] *= fj[j];
    }

    // ---- P = exp(S - m), pack to bf16 words pw[cb][w2] ----
    unsigned pw[4][2];
#pragma unroll
    for (int cb = 0; cb < 4; ++cb) {
#pragma unroll
      for (int w2 = 0; w2 < 2; ++w2) {
        union { __bf16 h[2]; unsigned u; } cu;
        cu.h[0] = (__bf16)__expf(sacc[cb][2 * w2] - mr);
        cu.h[1] = (__bf16)__expf(sacc[cb][2 * w2 + 1] - mr);
        pw[cb][w2] = cu.u;
      }
    }

    // ---- in-register exchange: build PV A-fragment P[q=l15][k=kf*32+lg*8+e]
    const int srcA = ((lg & 1) * 2) * 16 + l15;
    const int srcB = srcA + 16;
    const bool hi = (lg >> 1) & 1;
#pragma unroll
    for (int kf = 0; kf < 2; ++kf) {
      unsigned t0a = __shfl((int)pw[kf * 2][0], srcA, 64);
      unsigned t0b = __shfl((int)pw[kf * 2 + 1][0], srcA, 64);
      unsigned t1a = __shfl((int)pw[kf * 2][1], srcA, 64);
      unsigned t1b = __shfl((int)pw[kf * 2 + 1][1], srcA, 64);
      unsigned t2a = __shfl((int)pw[kf * 2][0], srcB, 64);
      unsigned t2b = __shfl((int)pw[kf * 2 + 1][0], srcB, 64);
      unsigned t3a = __shfl((int)pw[kf * 2][1], srcB, 64);
      unsigned t3b = __shfl((int)pw[kf * 2 + 1][1], srcB, 64);
      union { unsigned u[4]; bf16x8 v; } pa;
      pa.u[0] = hi ? t0b : t0a;
      pa.u[1] = hi ? t1b : t1a;
      pa.u[2] = hi ? t2b : t2a;
      pa.u[3] = hi ? t3b : t3a;
      __builtin_amdgcn_s_setprio(1);
      lacc = __builtin_amdgcn_mfma_f32_16x16x32_bf16(pa.v, onesf, lacc, 0, 0, 0);
#pragma unroll
      for (int db = 0; db < 4; ++db) {
        int row = db * 16 + l15;
        bf16x8 vf = *(const bf16x8*)&Vs[buf][row * 64 + (((kf * 4 + lg) ^ (row & 7)) * 8)];
        oacc[db] = __builtin_amdgcn_mfma_f32_16x16x32_bf16(pa.v, vf, oacc[db], 0, 0, 0);
      }
      __builtin_amdgcn_s_setprio(0);
    }
    __syncthreads();   // drains stage(t+1) vmem writes + protects buf reuse
    buf ^= 1;
  }

  // ---- write unnormalized partial ----
  const size_t obase = (((size_t)(z * Bc * Hc + bh)) * Sc + qbase) * DHc;
#pragma unroll
  for (int db = 0; db < 4; ++db)
#pragma unroll
    for (int j = 0; j < 4; ++j)
      Opart[obase + (size_t)(lg * 4 + j) * DHc + db * 16 + l15] = (__bf16)oacc[db][j];
  const int row0 = (z * Bc * Hc + bh) * Sc + qbase;
  if (lg == 0) mpart[row0 + l15] = mr;      // m held at lane l15 = q
  if (l15 == 0) {
#pragma unroll
    for (int j = 0; j < 4; ++j) lpart[row0 + lg * 4 + j] = lacc[j];
  }
}

// ---------------- combine split partials -> bf16 [B,S,D] (vectorized) -------
__global__ __launch_bounds__(256) void attn_combine(
    const __bf16* __restrict__ Opart, const float* __restrict__ mpart,
    const float* __restrict__ lpart, __bf16* __restrict__ out) {
  int t = blockIdx.x * 256 + threadIdx.x;  // over BH*S*8 (8 elems per thread)
  int g = t & 7;
  int row = t >> 3;          // bh*Sc + s
  int bh = row >> 11, s = row & (Sc - 1);
  constexpr int RSTRIDE = Bc * Hc * Sc;  // rows per split
  float m0 = mpart[row], m1 = mpart[RSTRIDE + row];
  float l0 = lpart[row], l1 = lpart[RSTRIDE + row];
  float M = fmaxf(m0, m1);
  float e0 = __expf(m0 - M), e1 = __expf(m1 - M);
  float inv = 1.0f / (e0 * l0 + e1 * l1);
  bf16x8 o0 = *(const bf16x8*)&Opart[(size_t)row * DHc + g * 8];
  bf16x8 o1 = *(const bf16x8*)&Opart[((size_t)RSTRIDE + row) * DHc + g * 8];
  bf16x8 r;
#pragma unroll
  for (int e = 0; e < 8; ++e)
    r[e] = (__bf16)((e0 * (float)o0[e] + e1 * (float)o1[e]) * inv);
  int b = bh >> 3, h = bh & 7;
  *(bf16x8*)&out[(((size_t)b * Sc + s)) * Dc + h * DHc + g * 8] = r;
}

// ---------------- residual add + LayerNorm (vectorized, 2 rows/block) -------
// x_out = LN((res + res2) * mask + xin) * g + b ; writes fp32 and bf16.
__global__ __launch_bounds__(256) void add_ln_kernel(
    const float* __restrict__ res, const float* __restrict__ res2,
    const int* __restrict__ rmask, const float* __restrict__ xin,
    const float* __restrict__ g, const float* __restrict__ bb,
    float* __restrict__ xo, __bf16* __restrict__ xbo) {
  const int tid = threadIdx.x;
  const int rl = tid >> 7;                 // row within pair (0/1)
  const int row = blockIdx.x * 2 + rl;
  const int ci = (tid & 127) * 4;          // column start
  const size_t base = (size_t)row * Dc + ci;
  const float4 a = *(const float4*)(res + base);
  const float4 a2 = *(const float4*)(res2 + base);
  const float4 xv = *(const float4*)(xin + base);
  const float mfac = (float)rmask[row];
  float4 v;
  v.x = (a.x + a2.x) * mfac + xv.x;
  v.y = (a.y + a2.y) * mfac + xv.y;
  v.z = (a.z + a2.z) * mfac + xv.z;
  v.w = (a.w + a2.w) * mfac + xv.w;
  float s = v.x + v.y + v.z + v.w;
#pragma unroll
  for (int d = 1; d < 64; d <<= 1) s += __shfl_xor(s, d, 64);
  __shared__ float red[4], red2[4];
  if ((tid & 63) == 0) red[tid >> 6] = s;
  __syncthreads();
  float mean = (red[rl * 2] + red[rl * 2 + 1]) * (1.0f / Dc);
  float4 dv;
  dv.x = v.x - mean; dv.y = v.y - mean; dv.z = v.z - mean; dv.w = v.w - mean;
  float qq = dv.x * dv.x + dv.y * dv.y + dv.z * dv.z + dv.w * dv.w;
#pragma unroll
  for (int d = 1; d < 64; d <<= 1) qq += __shfl_xor(qq, d, 64);
  if ((tid & 63) == 0) red2[tid >> 6] = qq;
  __syncthreads();
  float var = (red2[rl * 2] + red2[rl * 2 + 1]) * (1.0f / Dc);
  float rs = rsqrtf(var + 1e-5f);
  const float4 gv = *(const float4*)(g + ci);
  const float4 bv = *(const float4*)(bb + ci);
  float4 ov;
  ov.x = dv.x * rs * gv.x + bv.x;
  ov.y = dv.y * rs * gv.y + bv.y;
  ov.z = dv.z * rs * gv.z + bv.z;
  ov.w = dv.w * rs * gv.w + bv.w;
  *(float4*)(xo + base) = ov;
  bf16x4 ob;
  ob[0] = (__bf16)ov.x; ob[1] = (__bf16)ov.y; ob[2] = (__bf16)ov.z; ob[3] = (__bf16)ov.w;
  *(bf16x4*)(xbo + base) = ob;
}

extern "C" void kernel_launch(void* const* d_in, const int* in_sizes, int n_in,
                              void* d_out, int out_size, void* d_ws, size_t ws_size,
                              hipStream_t stream) {
  (void)in_sizes; (void)n_in; (void)out_size; (void)ws_size;
  const float* query = (const float*)d_in[0];
  const float* key   = (const float*)d_in[1];
  const int* qmask   = (const int*)d_in[2];
  const int* kmask   = (const int*)d_in[3];
  const float* Wq = (const float*)d_in[4];
  const float* bq = (const float*)d_in[5];
  const float* Wk = (const float*)d_in[6];
  const float* bk = (const float*)d_in[7];
  const float* Wv = (const float*)d_in[8];
  const float* bv = (const float*)d_in[9];
  const float* Wo = (const float*)d_in[10];
  const float* bo = (const float*)d_in[11];
  const float* ln1g = (const float*)d_in[12];
  const float* ln1b = (const float*)d_in[13];
  const float* fw1 = (const float*)d_in[14];
  const float* fb1 = (const float*)d_in[15];
  const float* fw2 = (const float*)d_in[16];
  const float* fb2 = (const float*)d_in[17];
  const float* ln2g = (const float*)d_in[18];
  const float* ln2b = (const float*)d_in[19];

  char* ws = (char*)d_ws;
  size_t off = 0;
  auto carve = [&](size_t bytes) -> void* {
    void* p = ws + off;
    off += (bytes + 255) & ~(size_t)255;
    return p;
  };
  float* x_f    = (float*)carve((size_t)Mc * Dc * 4);
  float* tmp_f  = (float*)carve((size_t)2 * Mc * Dc * 4);  // split-K partials z=0,1
  __bf16* x_b   = (__bf16*)carve((size_t)Mc * Dc * 2);
  __bf16* key_b = (__bf16*)carve((size_t)Mc * Dc * 2);
  __bf16* q_b   = (__bf16*)carve((size_t)Mc * Dc * 2);
  __bf16* at_b  = (__bf16*)carve((size_t)Mc * Dc * 2);
  __bf16* h_b   = (__bf16*)carve((size_t)Mc * FFc * 2);
  __bf16* k_all = (__bf16*)carve((size_t)LAYERS * Mc * Dc * 2);
  __bf16* vt_all= (__bf16*)carve((size_t)LAYERS * Mc * Dc * 2);
  __bf16* wq_b  = (__bf16*)carve((size_t)LAYERS * Dc * Dc * 2);
  __bf16* wkv_b = (__bf16*)carve((size_t)LAYERS * 2 * Dc * Dc * 2);
  __bf16* wo_b  = (__bf16*)carve((size_t)LAYERS * Dc * Dc * 2);
  __bf16* w1_b  = (__bf16*)carve((size_t)LAYERS * FFc * Dc * 2);
  __bf16* w2_b  = (__bf16*)carve((size_t)LAYERS * Dc * FFc * 2);
  float* ml_f   = (float*)carve((size_t)NS * Bc * Hc * Sc * 4 * 2);  // m,l partials
  float* kb_f   = (float*)carve((size_t)Bc * Sc * 4);                // key bias

  __bf16* opart_b = h_b;  // reuse (free during attention)
  float* mpart_f = ml_f;
  float* lpart_f = ml_f + (size_t)NS * Bc * Hc * Sc;
  float* tmp2_f = tmp_f + (size_t)Mc * Dc;

  // fused conversions: 19922944 elements / 4 per thread / 256 per block
  cvt_all<<<19456, 256, 0, stream>>>(Wq, Wo, fw1, fw2, query, key,
                                     wq_b, wo_b, w1_b, w2_b, x_b, key_b, x_f);
  cvt_kv_kernel<<<LAYERS * 2 * Dc * Dc / 1024, 256, 0, stream>>>(Wk, Wv, wkv_b);
  kbias_kernel<<<Bc * Sc / 256, 256, 0, stream>>>(kmask, kb_f, Bc * Sc);

  const dim3 blk(256);
  const dim3 blkA(512);
  const dim3 gP64(Dc / 64, Mc / 64);                // 512 blocks (Q proj)
  const dim3 gOP(Dc / 64, Mc / 64, 2);              // O-proj split-K, 1024 blocks
  const dim3 gFF2(Dc / 64, Mc / 64, 2);             // FFN2 split-K, 1024 blocks
  const dim3 gKV(LAYERS * 2 * Dc / 128, Mc / 64);   // 48 x 64 = 3072 blocks
  const dim3 gFF1(FFc / 128, Mc / 64);              // 64x128 tiles, 1024 blocks
  const dim3 gAttn(Sc / 128 * Bc * Hc * NS);        // 512, 1-D + XCD swizzle
  const dim3 gComb(Bc * Hc * Sc * 8 / 256);         // 1024, 8 elems/thread
  const dim3 gLN(Mc / 2);                           // 2 rows per block

  // all layers' K/V projections in one batched GEMM (depends only on `key`)
  gemm_bt<64, 128, 2, 4, 6><<<gKV, blk, 0, stream>>>(
      key_b, wkv_b, bk, bv, nullptr, k_all, vt_all, 1.0f,
      Mc, LAYERS * 2 * Dc, Dc, Dc);

  for (int i = 0; i < LAYERS; ++i) {
    const __bf16* wq_i = wq_b + (size_t)i * Dc * Dc;
    const __bf16* wo_i = wo_b + (size_t)i * Dc * Dc;
    const __bf16* w1_i = w1_b + (size_t)i * FFc * Dc;
    const __bf16* w2_i = w2_b + (size_t)i * Dc * FFc;
    const __bf16* k_i  = k_all + (size_t)i * Mc * Dc;
    const __bf16* vt_i = vt_all + (size_t)i * Mc * Dc;

    gemm_bt<64, 64, 2, 2, 1><<<gP64, blk, 0, stream>>>(
        x_b, wq_i, bq + i * Dc, nullptr, nullptr, q_b, nullptr, 0.125f,
        Mc, Dc, Dc, Dc);
    attn_kernel<<<gAttn, blkA, 0, stream>>>(q_b, k_i, vt_i, kb_f,
                                            opart_b, mpart_f, lpart_f);
    attn_combine<<<gComb, blk, 0, stream>>>(opart_b, mpart_f, lpart_f, at_b);
    gemm_bt<64, 64, 2, 2, 0><<<gOP, blk, 0, stream>>>(
        at_b, wo_i, bo + i * Dc, nullptr, tmp_f, nullptr, nullptr, 1.0f,
        Mc, Dc, Dc / 2, Dc);
    add_ln_kernel<<<gLN, blk, 0, stream>>>(tmp_f, tmp2_f, qmask, x_f,
                                           ln1g + i * Dc, ln1b + i * Dc, x_f, x_b);
    gemm_bt<64, 128, 2, 4, 4><<<gFF1, blk, 0, stream>>>(
        x_b, w1_i, fb1 + i * FFc, nullptr, nullptr, h_b, nullptr, 1.0f,
        Mc, FFc, Dc, Dc);
    gemm_bt<64, 64, 2, 2, 0><<<gFF2, blk, 0, stream>>>(
        h_b, w2_i, fb2 + i * Dc, nullptr, tmp_f, nullptr, nullptr, 1.0f,
        Mc, Dc, FFc / 2, FFc);
    add_ln_kernel<<<gLN, blk, 0, stream>>>(tmp_f, tmp2_f, qmask, x_f,
                                           ln2g + i * Dc, ln2b + i * Dc, x_f, x_b);
  }
  hipMemcpyAsync(d_out, x_f, (size_t)Mc * Dc * 4, hipMemcpyDeviceToDevice, stream);
}

// Round 16
// 750.980 us; speedup vs baseline: 1.2208x; 1.0156x over previous
//
#include <hip/hip_runtime.h>
#include <stdint.h>

constexpr int LAYERS = 6;
constexpr int Bc = 2, Sc = 2048, Dc = 512, Hc = 8, DHc = 64, FFc = 2048;
constexpr int Mc = Bc * Sc;  // 4096
constexpr int NS = 2;        // attention K-splits
constexpr int KCHUNK = Sc / NS;  // 1024

typedef __attribute__((ext_vector_type(8))) __bf16 bf16x8;
typedef __attribute__((ext_vector_type(4))) __bf16 bf16x4;
typedef __attribute__((ext_vector_type(4))) float f32x4;

__device__ __forceinline__ void async_ld16(const void* g, void* lds) {
  __builtin_amdgcn_global_load_lds(
      (const __attribute__((address_space(1))) uint32_t*)g,
      (__attribute__((address_space(3))) uint32_t*)lds, 16, 0, 0);
}

// ---------------- fused fp32 -> bf16 conversion of all inputs ----------------
// Segments: Wq | Wo | fw1 | fw2 | query(+f32 copy) | key
__global__ __launch_bounds__(256) void cvt_all(
    const float* __restrict__ Wq, const float* __restrict__ Wo,
    const float* __restrict__ fw1, const float* __restrict__ fw2,
    const float* __restrict__ query, const float* __restrict__ key,
    __bf16* __restrict__ wq_b, __bf16* __restrict__ wo_b,
    __bf16* __restrict__ w1_b, __bf16* __restrict__ w2_b,
    __bf16* __restrict__ x_b, __bf16* __restrict__ key_b,
    float* __restrict__ x_f) {
  size_t i = ((size_t)blockIdx.x * 256 + threadIdx.x) * 4;
  constexpr size_t nW = (size_t)LAYERS * Dc * Dc;   // 1572864
  constexpr size_t nF = (size_t)LAYERS * FFc * Dc;  // 6291456
  constexpr size_t nX = (size_t)Mc * Dc;            // 2097152
  const float* src;
  __bf16* dst;
  float* fdst = nullptr;
  if (i < nW) { src = Wq + i; dst = wq_b + i; }
  else if (i < 2 * nW) { size_t j = i - nW; src = Wo + j; dst = wo_b + j; }
  else if (i < 2 * nW + nF) { size_t j = i - 2 * nW; src = fw1 + j; dst = w1_b + j; }
  else if (i < 2 * nW + 2 * nF) { size_t j = i - 2 * nW - nF; src = fw2 + j; dst = w2_b + j; }
  else if (i < 2 * nW + 2 * nF + nX) {
    size_t j = i - 2 * nW - 2 * nF;
    src = query + j; dst = x_b + j; fdst = x_f + j;
  } else {
    size_t j = i - 2 * nW - 2 * nF - nX;
    src = key + j; dst = key_b + j;
  }
  const float4 v = *(const float4*)src;
  bf16x4 o;
  o[0] = (__bf16)v.x; o[1] = (__bf16)v.y; o[2] = (__bf16)v.z; o[3] = (__bf16)v.w;
  *(bf16x4*)dst = o;
  if (fdst) *(float4*)fdst = v;
}

// interleave all layers' Wk,Wv into one bf16 buffer [L][2][D][D]
__global__ __launch_bounds__(256) void cvt_kv_kernel(const float* __restrict__ Wk,
                                                     const float* __restrict__ Wv,
                                                     __bf16* __restrict__ out) {
  size_t i = ((size_t)blockIdx.x * 256 + threadIdx.x) * 4;
  int n = (int)(i / ((size_t)Dc * Dc));  // lyr*2 + p
  int lyr = n >> 1, p = n & 1;
  size_t idx = i - (size_t)n * Dc * Dc;
  const float* src = (p ? Wv : Wk) + (size_t)lyr * Dc * Dc + idx;
  const float4 v = *(const float4*)src;
  bf16x4 o;
  o[0] = (__bf16)v.x; o[1] = (__bf16)v.y; o[2] = (__bf16)v.z; o[3] = (__bf16)v.w;
  *(bf16x4*)(out + i) = o;
}

// key mask -> additive bias
__global__ __launch_bounds__(256) void kbias_kernel(const int* __restrict__ km,
                                                    float* __restrict__ kb, int n) {
  int i = blockIdx.x * 256 + threadIdx.x;
  if (i < n) kb[i] = km[i] ? 0.f : -1e30f;
}

// ---------------- GEMM: C[M,N] = A[M,K] @ W[N,K]^T + bias, fused epilogues ----
// BK=64, 2-phase double-buffered LDS, both-sides XOR swizzle (slot ^ (row&7)).
// Split-K via blockIdx.z: K = per-block chunk, Kstride = full row stride.
// EPI: 0 = f32 row-major partial (outf + z*M*N), bias at z==0
//      1 = bf16 split-head [B,H,S,DH], value *= scale    (Q projection)
//      4 = bf16 row-major, leaky-relu(0.01)              (FFN1)
//      6 = batched KV: N = L*1024; K -> outb [L,B,H,S,DH];
//          V -> outb2 [L,B,H,DH,S] via LDS-transposed coalesced stores
template <int BM, int BN, int WM, int WN, int EPI>
__global__ __launch_bounds__(256) void gemm_bt(
    const __bf16* __restrict__ A, const __bf16* __restrict__ W,
    const float* __restrict__ bias, const float* __restrict__ bias2,
    float* __restrict__ outf, __bf16* __restrict__ outb,
    __bf16* __restrict__ outb2, float scale,
    int M, int N, int K, int Kstride) {
  constexpr int BK = 64;
  __shared__ __bf16 As[2][BM * BK];
  __shared__ __bf16 Bs[2][BN * BK];
  const int tid = threadIdx.x;
  const int l15 = tid & 15;
  const int lg = (tid & 63) >> 4;
  const int w = tid >> 6;
  const int wm = w >> 1, wn = w & 1;
  const int tm = blockIdx.y * BM;
  const int tn = blockIdx.x * BN;
  const int z = blockIdx.z;
  const __bf16* Ap = A + (size_t)tm * Kstride + (size_t)z * K;
  const __bf16* Wp = W + (size_t)tn * Kstride + (size_t)z * K;
  f32x4 acc[WM][WN] = {};

  auto stage = [&](int k0, int bf) {
#pragma unroll
    for (int c = 0; c < BM * 8 / 256; ++c) {
      int cc = c * 256 + tid;
      int r = cc >> 3, s = cc & 7;
      int ss = s ^ (r & 7);  // inverse-swizzled source slot
      async_ld16(Ap + (size_t)r * Kstride + k0 + ss * 8, &As[bf][cc * 8]);
    }
#pragma unroll
    for (int c = 0; c < BN * 8 / 256; ++c) {
      int cc = c * 256 + tid;
      int r = cc >> 3, s = cc & 7;
      int ss = s ^ (r & 7);
      async_ld16(Wp + (size_t)r * Kstride + k0 + ss * 8, &Bs[bf][cc * 8]);
    }
  };

  const int nk = K / BK;
  stage(0, 0);
  __syncthreads();
  int buf = 0;
  for (int t = 0; t < nk; ++t) {
    if (t + 1 < nk) stage((t + 1) * BK, buf ^ 1);
    bf16x8 af[WM][2], bfr[WN][2];
#pragma unroll
    for (int i = 0; i < WM; ++i) {
      int row = wm * WM * 16 + i * 16 + l15;
#pragma unroll
      for (int kf = 0; kf < 2; ++kf)
        af[i][kf] = *(const bf16x8*)&As[buf][row * 64 + (((kf * 4 + lg) ^ (row & 7)) * 8)];
    }
#pragma unroll
    for (int j = 0; j < WN; ++j) {
      int row = wn * WN * 16 + j * 16 + l15;
#pragma unroll
      for (int kf = 0; kf < 2; ++kf)
        bfr[j][kf] = *(const bf16x8*)&Bs[buf][row * 64 + (((kf * 4 + lg) ^ (row & 7)) * 8)];
    }
#pragma unroll
    for (int kf = 0; kf < 2; ++kf)
#pragma unroll
      for (int i = 0; i < WM; ++i)
#pragma unroll
        for (int j = 0; j < WN; ++j)
          acc[i][j] = __builtin_amdgcn_mfma_f32_16x16x32_bf16(af[i][kf], bfr[j][kf], acc[i][j], 0, 0, 0);
    __syncthreads();
    buf ^= 1;
  }

  if constexpr (EPI == 6) {
    const bool isV = ((tn & 1023) >= 512);
    const int lyr = tn >> 10;
    const int b = tm >> 11;
    const int sbase = tm & (Sc - 1);
    if (isV) {
      // V half: transpose 64(s) x 128(d) tile through LDS, coalesced stores.
      __bf16* T = (__bf16*)&As[0][0];  // [128 d][64 s], 16B-slot XOR swizzle
#pragma unroll
      for (int i = 0; i < WM; ++i) {
#pragma unroll
        for (int j = 0; j < WN; ++j) {
          const int d = wn * WN * 16 + j * 16 + l15;   // 0..127
          const int dg = (tn & 511) + d;               // 0..511 within layer V
          const float bv = bias2[lyr * 512 + dg];
          const int s0 = wm * WM * 16 + i * 16 + lg * 4;
          bf16x4 pk;
#pragma unroll
          for (int r = 0; r < 4; ++r) pk[r] = (__bf16)(acc[i][j][r] + bv);
          const int slot = (s0 >> 3) ^ (d & 7);
          *(bf16x4*)&T[d * 64 + slot * 8 + (s0 & 7)] = pk;
        }
      }
      __syncthreads();
      const int rr = tid >> 3;   // 0..31
      const int c8 = tid & 7;    // s-slot
#pragma unroll
      for (int pass = 0; pass < 4; ++pass) {
        const int d = pass * 32 + rr;
        const int slot = c8 ^ (d & 7);
        bf16x8 v8 = *(const bf16x8*)&T[d * 64 + slot * 8];
        const int dg = (tn & 511) + d;
        const int h = dg >> 6, dh = dg & 63;
        *(bf16x8*)&outb2[((((size_t)(lyr * Bc + b) * Hc + h)) * DHc + dh) * Sc +
                         sbase + c8 * 8] = v8;
      }
    } else {
      // K half: near-coalesced direct stores (789-baseline version)
#pragma unroll
      for (int i = 0; i < WM; ++i) {
#pragma unroll
        for (int j = 0; j < WN; ++j) {
          const int d = wn * WN * 16 + j * 16 + l15;
          const int dg = (tn & 511) + d;
          const float bv = bias[lyr * 512 + dg];
          const int h = dg >> 6, dh = dg & 63;
#pragma unroll
          for (int r = 0; r < 4; ++r) {
            const int s = sbase + wm * WM * 16 + i * 16 + lg * 4 + r;
            outb[((((size_t)(lyr * Bc + b) * Hc + h)) * Sc + s) * DHc + dh] =
                (__bf16)(acc[i][j][r] + bv);
          }
        }
      }
    }
    return;
  }

#pragma unroll
  for (int i = 0; i < WM; ++i) {
#pragma unroll
    for (int j = 0; j < WN; ++j) {
      const int n = tn + wn * WN * 16 + j * 16 + l15;
      float bv;
      if constexpr (EPI == 0) {
        bv = (z == 0) ? bias[n] : 0.f;
      } else {
        bv = bias[n];
      }
#pragma unroll
      for (int r = 0; r < 4; ++r) {
        const int m = tm + wm * WM * 16 + i * 16 + lg * 4 + r;
        float v = acc[i][j][r] + bv;
        if constexpr (EPI == 0) {
          outf[(size_t)z * M * N + (size_t)m * N + n] = v;
        } else if constexpr (EPI == 1) {
          int b = m >> 11, s = m & (Sc - 1);
          int h = n >> 6, dh = n & 63;
          outb[(((size_t)(b * Hc + h)) * Sc + s) * DHc + dh] = (__bf16)(v * scale);
        } else if constexpr (EPI == 4) {
          float lv = v > 0.f ? v : 0.01f * v;
          outb[(size_t)m * N + n] = (__bf16)lv;
        }
      }
    }
  }
}

// ---------------- flash attention with K-split, swapped QK^T ----------------
// 8-wave blocks (512 threads, 128 q rows). KBLK=128: each staged tile holds
// 128 keys, processed as two 64-wide halves with ONE barrier + ONE stage call
// per 128 keys (halves the barrier/vmcnt-drain count vs KBLK=64). K rows use
// slot^(r&7) swizzle (8 slots/row); V rows are 128-elem so slot^(d&15)
// (16 slots/row) spreads all 32 banks. Mask bias loaded in-loop (V0).
__global__ __launch_bounds__(512, 2) void attn_kernel(
    const __bf16* __restrict__ q, const __bf16* __restrict__ k,
    const __bf16* __restrict__ vt, const float* __restrict__ kb,
    __bf16* __restrict__ Opart, float* __restrict__ mpart,
    float* __restrict__ lpart) {
  const int bid = blockIdx.x;
  const int o = (bid & 7) * 64 + (bid >> 3);  // bijective (512 = 8*64)
  const int qb = o & 15;     // 16 q-tiles of 128 rows
  const int p = o >> 4;      // 0..31 = bh*NS + z
  const int bh = p >> 1;
  const int z = p & 1;
  const int b = bh >> 3;
  const int w = threadIdx.x >> 6;   // 0..7
  const int l = threadIdx.x & 63;
  const int l15 = l & 15;
  const int lg = l >> 4;
  const int tid = threadIdx.x;
  const int qbase = qb * 128 + w * 16;
  const int k0 = z * KCHUNK;

  const __bf16* qp = q + ((size_t)bh * Sc + qbase) * DHc;
  const __bf16* kp = k + (size_t)bh * Sc * DHc;
  const __bf16* vp = vt + (size_t)bh * DHc * Sc;
  const float* kbp = kb + (size_t)b * Sc;

  bf16x8 qf[2];
  qf[0] = *(const bf16x8*)(qp + l15 * DHc + lg * 8);
  qf[1] = *(const bf16x8*)(qp + l15 * DHc + 32 + lg * 8);

  bf16x8 onesf;
#pragma unroll
  for (int i = 0; i < 8; ++i) onesf[i] = (__bf16)1.0f;

  f32x4 oacc[4] = {};
  f32x4 lacc = {};
  float mr = -1e30f;  // running max for q = l15 (converged across lane groups)

  __shared__ __bf16 Ks[2][8192];   // [128 k-rows][64 dh]
  __shared__ __bf16 Vs[2][8192];   // [64 d-rows][128 s]

  auto stage = [&](int t, int bf) {
    const int kt = k0 + t * 128;
#pragma unroll
    for (int ii = 0; ii < 2; ++ii) {
      int i = ii * 512 + tid;          // K slot id 0..1023
      int r = i >> 3;                  // k-row 0..127
      int ss = (i & 7) ^ (r & 7);
      async_ld16(kp + (size_t)(kt + r) * DHc + ss * 8, &Ks[bf][i * 8]);
      int d = i >> 4;                  // d-row 0..63
      int vs = (i & 15) ^ (d & 15);
      async_ld16(vp + (size_t)d * Sc + kt + vs * 8, &Vs[bf][i * 8]);
    }
  };

  stage(0, 0);
  __syncthreads();

  constexpr int NT = KCHUNK / 128;   // 8
  int buf = 0;
  for (int t = 0; t < NT; ++t) {
    if (t + 1 < NT) stage(t + 1, buf ^ 1);
#pragma unroll
    for (int h2 = 0; h2 < 2; ++h2) {
      const int kt = k0 + t * 128 + h2 * 64;

      // mask bias (in-loop, V0): 4 aligned float4 loads
      float4 mb4[4];
#pragma unroll
      for (int cb = 0; cb < 4; ++cb)
        mb4[cb] = *(const float4*)&kbp[kt + cb * 16 + lg * 4];

      // ---- swapped QK^T: S[k][q], lane holds k=cb*16+lg*4+r, q=l15 ----
      f32x4 sacc[4] = {};
      __builtin_amdgcn_s_setprio(1);
#pragma unroll
      for (int kf = 0; kf < 2; ++kf) {
#pragma unroll
        for (int cb = 0; cb < 4; ++cb) {
          int row = h2 * 64 + cb * 16 + l15;
          bf16x8 kfr = *(const bf16x8*)&Ks[buf][row * 64 + (((kf * 4 + lg) ^ (row & 7)) * 8)];
          sacc[cb] = __builtin_amdgcn_mfma_f32_16x16x32_bf16(kfr, qf[kf], sacc[cb], 0, 0, 0);
        }
      }
      __builtin_amdgcn_s_setprio(0);
      sacc[0][0] += mb4[0].x; sacc[0][1] += mb4[0].y; sacc[0][2] += mb4[0].z; sacc[0][3] += mb4[0].w;
      sacc[1][0] += mb4[1].x; sacc[1][1] += mb4[1].y; sacc[1][2] += mb4[1].z; sacc[1][3] += mb4[1].w;
      sacc[2][0] += mb4[2].x; sacc[2][1] += mb4[2].y; sacc[2][2] += mb4[2].z; sacc[2][3] += mb4[2].w;
      sacc[3][0] += mb4[3].x; sacc[3][1] += mb4[3].y; sacc[3][2] += mb4[3].z; sacc[3][3] += mb4[3].w;

      // ---- row max: 15 local fmax + 2 shfl_xor ----
      float mx = sacc[0][0];
#pragma unroll
      for (int cb = 0; cb < 4; ++cb)
#pragma unroll
        for (int r = 0; r < 4; ++r) mx = fmaxf(mx, sacc[cb][r]);
      mx = fmaxf(mx, __shfl_xor(mx, 16, 64));
      mx = fmaxf(mx, __shfl_xor(mx, 32, 64));

      if (__any(mx > mr + 8.f)) {   // defer-max: rare rescale
        float mn = fmaxf(mr, mx);
        float f = __expf(mr - mn);
        mr = mn;
        float fj[4];
#pragma unroll
        for (int j = 0; j < 4; ++j) fj[j] = __shfl(f, lg * 4 + j, 64);
#pragma unroll
        for (int j = 0; j < 4; ++j) lacc[j] *= fj[j];
#pragma unroll
        for (int db = 0; db < 4; ++db)
#pragma unroll
          for (int j = 0; j < 4; ++j) oacc[db][j] *= fj[j];
      }

      // ---- P = exp(S - m), pack to bf16 words ----
      unsigned pw[4][2];
#pragma unroll
      for (int cb = 0; cb < 4; ++cb) {
#pragma unroll
        for (int w2 = 0; w2 < 2; ++w2) {
          union { __bf16 h[2]; unsigned u; } cu;
          cu.h[0] = (__bf16)__expf(sacc[cb][2 * w2] - mr);
          cu.h[1] = (__bf16)__expf(sacc[cb][2 * w2 + 1] - mr);
          pw[cb][w2] = cu.u;
        }
      }

      // ---- in-register exchange -> PV A-fragment ----
      const int srcA = ((lg & 1) * 2) * 16 + l15;
      const int srcB = srcA + 16;
      const bool hi = (lg >> 1) & 1;
#pragma unroll
      for (int kf = 0; kf < 2; ++kf) {
        unsigned t0a = __shfl((int)pw[kf * 2][0], srcA, 64);
        unsigned t0b = __shfl((int)pw[kf * 2 + 1][0], srcA, 64);
        unsigned t1a = __shfl((int)pw[kf * 2][1], srcA, 64);
        unsigned t1b = __shfl((int)pw[kf * 2 + 1][1], srcA, 64);
        unsigned t2a = __shfl((int)pw[kf * 2][0], srcB, 64);
        unsigned t2b = __shfl((int)pw[kf * 2 + 1][0], srcB, 64);
        unsigned t3a = __shfl((int)pw[kf * 2][1], srcB, 64);
        unsigned t3b = __shfl((int)pw[kf * 2 + 1][1], srcB, 64);
        union { unsigned u[4]; bf16x8 v; } pa;
        pa.u[0] = hi ? t0b : t0a;
        pa.u[1] = hi ? t1b : t1a;
        pa.u[2] = hi ? t2b : t2a;
        pa.u[3] = hi ? t3b : t3a;
        __builtin_amdgcn_s_setprio(1);
        lacc = __builtin_amdgcn_mfma_f32_16x16x32_bf16(pa.v, onesf, lacc, 0, 0, 0);
#pragma unroll
        for (int db = 0; db < 4; ++db) {
          int d = db * 16 + l15;
          int slot = (h2 * 8 + kf * 4 + lg) ^ (d & 15);
          bf16x8 vf = *(const bf16x8*)&Vs[buf][d * 128 + slot * 8];
          oacc[db] = __builtin_amdgcn_mfma_f32_16x16x32_bf16(pa.v, vf, oacc[db], 0, 0, 0);
        }
        __builtin_amdgcn_s_setprio(0);
      }
    }
    __syncthreads();   // drains stage(t+1) vmem writes + protects buf reuse
    buf ^= 1;
  }

  // ---- write unnormalized partial ----
  const size_t obase = (((size_t)(z * Bc * Hc + bh)) * Sc + qbase) * DHc;
#pragma unroll
  for (int db = 0; db < 4; ++db)
#pragma unroll
    for (int j = 0; j < 4; ++j)
      Opart[obase + (size_t)(lg * 4 + j) * DHc + db * 16 + l15] = (__bf16)oacc[db][j];
  const int row0 = (z * Bc * Hc + bh) * Sc + qbase;
  if (lg == 0) mpart[row0 + l15] = mr;      // m held at lane l15 = q
  if (l15 == 0) {
#pragma unroll
    for (int j = 0; j < 4; ++j) lpart[row0 + lg * 4 + j] = lacc[j];
  }
}

// ---------------- combine split partials -> bf16 [B,S,D] (vectorized) -------
__global__ __launch_bounds__(256) void attn_combine(
    const __bf16* __restrict__ Opart, const float* __restrict__ mpart,
    const float* __restrict__ lpart, __bf16* __restrict__ out) {
  int t = blockIdx.x * 256 + threadIdx.x;  // over BH*S*8 (8 elems per thread)
  int g = t & 7;
  int row = t >> 3;          // bh*Sc + s
  int bh = row >> 11, s = row & (Sc - 1);
  constexpr int RSTRIDE = Bc * Hc * Sc;  // rows per split
  float m0 = mpart[row], m1 = mpart[RSTRIDE + row];
  float l0 = lpart[row], l1 = lpart[RSTRIDE + row];
  float M = fmaxf(m0, m1);
  float e0 = __expf(m0 - M), e1 = __expf(m1 - M);
  float inv = 1.0f / (e0 * l0 + e1 * l1);
  bf16x8 o0 = *(const bf16x8*)&Opart[(size_t)row * DHc + g * 8];
  bf16x8 o1 = *(const bf16x8*)&Opart[((size_t)RSTRIDE + row) * DHc + g * 8];
  bf16x8 r;
#pragma unroll
  for (int e = 0; e < 8; ++e)
    r[e] = (__bf16)((e0 * (float)o0[e] + e1 * (float)o1[e]) * inv);
  int b = bh >> 3, h = bh & 7;
  *(bf16x8*)&out[(((size_t)b * Sc + s)) * Dc + h * DHc + g * 8] = r;
}

// ---------------- residual add + LayerNorm (vectorized, 2 rows/block) -------
// x_out = LN((res + res2) * mask + xin) * g + b ; writes fp32 and bf16.
__global__ __launch_bounds__(256) void add_ln_kernel(
    const float* __restrict__ res, const float* __restrict__ res2,
    const int* __restrict__ rmask, const float* __restrict__ xin,
    const float* __restrict__ g, const float* __restrict__ bb,
    float* __restrict__ xo, __bf16* __restrict__ xbo) {
  const int tid = threadIdx.x;
  const int rl = tid >> 7;                 // row within pair (0/1)
  const int row = blockIdx.x * 2 + rl;
  const int ci = (tid & 127) * 4;          // column start
  const size_t base = (size_t)row * Dc + ci;
  const float4 a = *(const float4*)(res + base);
  const float4 a2 = *(const float4*)(res2 + base);
  const float4 xv = *(const float4*)(xin + base);
  const float mfac = (float)rmask[row];
  float4 v;
  v.x = (a.x + a2.x) * mfac + xv.x;
  v.y = (a.y + a2.y) * mfac + xv.y;
  v.z = (a.z + a2.z) * mfac + xv.z;
  v.w = (a.w + a2.w) * mfac + xv.w;
  float s = v.x + v.y + v.z + v.w;
#pragma unroll
  for (int d = 1; d < 64; d <<= 1) s += __shfl_xor(s, d, 64);
  __shared__ float red[4], red2[4];
  if ((tid & 63) == 0) red[tid >> 6] = s;
  __syncthreads();
  float mean = (red[rl * 2] + red[rl * 2 + 1]) * (1.0f / Dc);
  float4 dv;
  dv.x = v.x - mean; dv.y = v.y - mean; dv.z = v.z - mean; dv.w = v.w - mean;
  float qq = dv.x * dv.x + dv.y * dv.y + dv.z * dv.z + dv.w * dv.w;
#pragma unroll
  for (int d = 1; d < 64; d <<= 1) qq += __shfl_xor(qq, d, 64);
  if ((tid & 63) == 0) red2[tid >> 6] = qq;
  __syncthreads();
  float var = (red2[rl * 2] + red2[rl * 2 + 1]) * (1.0f / Dc);
  float rs = rsqrtf(var + 1e-5f);
  const float4 gv = *(const float4*)(g + ci);
  const float4 bv = *(const float4*)(bb + ci);
  float4 ov;
  ov.x = dv.x * rs * gv.x + bv.x;
  ov.y = dv.y * rs * gv.y + bv.y;
  ov.z = dv.z * rs * gv.z + bv.z;
  ov.w = dv.w * rs * gv.w + bv.w;
  *(float4*)(xo + base) = ov;
  bf16x4 ob;
  ob[0] = (__bf16)ov.x; ob[1] = (__bf16)ov.y; ob[2] = (__bf16)ov.z; ob[3] = (__bf16)ov.w;
  *(bf16x4*)(xbo + base) = ob;
}

extern "C" void kernel_launch(void* const* d_in, const int* in_sizes, int n_in,
                              void* d_out, int out_size, void* d_ws, size_t ws_size,
                              hipStream_t stream) {
  (void)in_sizes; (void)n_in; (void)out_size; (void)ws_size;
  const float* query = (const float*)d_in[0];
  const float* key   = (const float*)d_in[1];
  const int* qmask   = (const int*)d_in[2];
  const int* kmask   = (const int*)d_in[3];
  const float* Wq = (const float*)d_in[4];
  const float* bq = (const float*)d_in[5];
  const float* Wk = (const float*)d_in[6];
  const float* bk = (const float*)d_in[7];
  const float* Wv = (const float*)d_in[8];
  const float* bv = (const float*)d_in[9];
  const float* Wo = (const float*)d_in[10];
  const float* bo = (const float*)d_in[11];
  const float* ln1g = (const float*)d_in[12];
  const float* ln1b = (const float*)d_in[13];
  const float* fw1 = (const float*)d_in[14];
  const float* fb1 = (const float*)d_in[15];
  const float* fw2 = (const float*)d_in[16];
  const float* fb2 = (const float*)d_in[17];
  const float* ln2g = (const float*)d_in[18];
  const float* ln2b = (const float*)d_in[19];

  char* ws = (char*)d_ws;
  size_t off = 0;
  auto carve = [&](size_t bytes) -> void* {
    void* p = ws + off;
    off += (bytes + 255) & ~(size_t)255;
    return p;
  };
  float* x_f    = (float*)carve((size_t)Mc * Dc * 4);
  float* tmp_f  = (float*)carve((size_t)2 * Mc * Dc * 4);  // split-K partials z=0,1
  __bf16* x_b   = (__bf16*)carve((size_t)Mc * Dc * 2);
  __bf16* key_b = (__bf16*)carve((size_t)Mc * Dc * 2);
  __bf16* q_b   = (__bf16*)carve((size_t)Mc * Dc * 2);
  __bf16* at_b  = (__bf16*)carve((size_t)Mc * Dc * 2);
  __bf16* h_b   = (__bf16*)carve((size_t)Mc * FFc * 2);
  __bf16* k_all = (__bf16*)carve((size_t)LAYERS * Mc * Dc * 2);
  __bf16* vt_all= (__bf16*)carve((size_t)LAYERS * Mc * Dc * 2);
  __bf16* wq_b  = (__bf16*)carve((size_t)LAYERS * Dc * Dc * 2);
  __bf16* wkv_b = (__bf16*)carve((size_t)LAYERS * 2 * Dc * Dc * 2);
  __bf16* wo_b  = (__bf16*)carve((size_t)LAYERS * Dc * Dc * 2);
  __bf16* w1_b  = (__bf16*)carve((size_t)LAYERS * FFc * Dc * 2);
  __bf16* w2_b  = (__bf16*)carve((size_t)LAYERS * Dc * FFc * 2);
  float* ml_f   = (float*)carve((size_t)NS * Bc * Hc * Sc * 4 * 2);  // m,l partials
  float* kb_f   = (float*)carve((size_t)Bc * Sc * 4);                // key bias

  __bf16* opart_b = h_b;  // reuse (free during attention)
  float* mpart_f = ml_f;
  float* lpart_f = ml_f + (size_t)NS * Bc * Hc * Sc;
  float* tmp2_f = tmp_f + (size_t)Mc * Dc;

  // fused conversions: 19922944 elements / 4 per thread / 256 per block
  cvt_all<<<19456, 256, 0, stream>>>(Wq, Wo, fw1, fw2, query, key,
                                     wq_b, wo_b, w1_b, w2_b, x_b, key_b, x_f);
  cvt_kv_kernel<<<LAYERS * 2 * Dc * Dc / 1024, 256, 0, stream>>>(Wk, Wv, wkv_b);
  kbias_kernel<<<Bc * Sc / 256, 256, 0, stream>>>(kmask, kb_f, Bc * Sc);

  const dim3 blk(256);
  const dim3 blkA(512);
  const dim3 gP64(Dc / 64, Mc / 64);                // 512 blocks (Q proj)
  const dim3 gOP(Dc / 64, Mc / 64, 2);              // O-proj split-K, 1024 blocks
  const dim3 gFF2(Dc / 64, Mc / 64, 2);             // FFN2 split-K, 1024 blocks
  const dim3 gKV(LAYERS * 2 * Dc / 128, Mc / 64);   // 48 x 64 = 3072 blocks
  const dim3 gFF1a(FFc / 64, Mc / 64);              // 64x64: 2048 blocks (even)
  const dim3 gFF1b(FFc / 128, Mc / 64);             // 64x128: 1024 blocks (odd)
  const dim3 gAttn(Sc / 128 * Bc * Hc * NS);        // 512, 1-D + XCD swizzle
  const dim3 gComb(Bc * Hc * Sc * 8 / 256);         // 1024, 8 elems/thread
  const dim3 gLN(Mc / 2);                           // 2 rows per block

  // all layers' K/V projections in one batched GEMM (depends only on `key`)
  gemm_bt<64, 128, 2, 4, 6><<<gKV, blk, 0, stream>>>(
      key_b, wkv_b, bk, bv, nullptr, k_all, vt_all, 1.0f,
      Mc, LAYERS * 2 * Dc, Dc, Dc);

  for (int i = 0; i < LAYERS; ++i) {
    const __bf16* wq_i = wq_b + (size_t)i * Dc * Dc;
    const __bf16* wo_i = wo_b + (size_t)i * Dc * Dc;
    const __bf16* w1_i = w1_b + (size_t)i * FFc * Dc;
    const __bf16* w2_i = w2_b + (size_t)i * Dc * FFc;
    const __bf16* k_i  = k_all + (size_t)i * Mc * Dc;
    const __bf16* vt_i = vt_all + (size_t)i * Mc * Dc;

    gemm_bt<64, 64, 2, 2, 1><<<gP64, blk, 0, stream>>>(
        x_b, wq_i, bq + i * Dc, nullptr, nullptr, q_b, nullptr, 0.125f,
        Mc, Dc, Dc, Dc);
    attn_kernel<<<gAttn, blkA, 0, stream>>>(q_b, k_i, vt_i, kb_f,
                                            opart_b, mpart_f, lpart_f);
    attn_combine<<<gComb, blk, 0, stream>>>(opart_b, mpart_f, lpart_f, at_b);
    gemm_bt<64, 64, 2, 2, 0><<<gOP, blk, 0, stream>>>(
        at_b, wo_i, bo + i * Dc, nullptr, tmp_f, nullptr, nullptr, 1.0f,
        Mc, Dc, Dc / 2, Dc);
    add_ln_kernel<<<gLN, blk, 0, stream>>>(tmp_f, tmp2_f, qmask, x_f,
                                           ln1g + i * Dc, ln1b + i * Dc, x_f, x_b);
    if (i & 1)
      gemm_bt<64, 128, 2, 4, 4><<<gFF1b, blk, 0, stream>>>(
          x_b, w1_i, fb1 + i * FFc, nullptr, nullptr, h_b, nullptr, 1.0f,
          Mc, FFc, Dc, Dc);
    else
      gemm_bt<64, 64, 2, 2, 4><<<gFF1a, blk, 0, stream>>>(
          x_b, w1_i, fb1 + i * FFc, nullptr, nullptr, h_b, nullptr, 1.0f,
          Mc, FFc, Dc, Dc);
    gemm_bt<64, 64, 2, 2, 0><<<gFF2, blk, 0, stream>>>(
        h_b, w2_i, fb2 + i * Dc, nullptr, tmp_f, nullptr, nullptr, 1.0f,
        Mc, Dc, FFc / 2, FFc);
    add_ln_kernel<<<gLN, blk, 0, stream>>>(tmp_f, tmp2_f, qmask, x_f,
                                           ln2g + i * Dc, ln2b + i * Dc, x_f, x_b);
  }
  hipMemcpyAsync(d_out, x_f, (size_t)Mc * Dc * 4, hipMemcpyDeviceToDevice, stream);
}